// Round 2
// baseline (793.110 us; speedup 1.0000x reference)
//
#include <hip/hip_runtime.h>
#include <hip/hip_fp16.h>

typedef _Float16 f16;
typedef _Float16 f16x8 __attribute__((ext_vector_type(8)));
typedef _Float16 f16x4 __attribute__((ext_vector_type(4)));
typedef float    f32x4 __attribute__((ext_vector_type(4)));

#define MFMA16(a, b, c) __builtin_amdgcn_mfma_f32_16x16x32_f16((a), (b), (c), 0, 0, 0)

__device__ __forceinline__ void gload16(const void* g, void* l) {
  __builtin_amdgcn_global_load_lds(
      (const __attribute__((address_space(1))) unsigned int*)g,
      (__attribute__((address_space(3))) unsigned int*)l,
      16, 0, 0);
}

__device__ __forceinline__ void bar() {
  asm volatile("" ::: "memory");
  __builtin_amdgcn_s_barrier();
  asm volatile("" ::: "memory");
}
#define VMWAIT(n) asm volatile("s_waitcnt vmcnt(" #n ")" ::: "memory")
#define LGKM0()   asm volatile("s_waitcnt lgkmcnt(0)" ::: "memory")

// ---------------- f32 -> f16 cast ----------------
__global__ __launch_bounds__(256) void cast_f32_to_f16(const float* __restrict__ src,
                                                       f16* __restrict__ dst, int n4) {
  int i = blockIdx.x * 256 + threadIdx.x;
  if (i >= n4) return;
  float4 v = reinterpret_cast<const float4*>(src)[i];
  f16x4 o = { (f16)v.x, (f16)v.y, (f16)v.z, (f16)v.w };
  reinterpret_cast<f16x4*>(dst)[i] = o;
}

// ============ 256x256 8-phase GEMM: C[M,N] = A[M,K] * B[N,K]^T, K=1024 ============
// 512 threads = 8 waves (2M x 4N), per-wave 128x64 output. BK=64, double-buffered
// 128 KiB LDS, st_16x32 XOR swizzle, counted vmcnt (4) at phases 4/8, setprio MFMA.
template <typename OutT>
__global__ __launch_bounds__(512, 2) void gemm_bt_8ph(const f16* __restrict__ A,
                                                      const f16* __restrict__ B,
                                                      OutT* __restrict__ C,
                                                      int N, int nby) {
  constexpr int K = 1024;
  constexpr int T = K / 64;     // 16 K-tiles
  constexpr int NIT = T / 2;    // 8 iterations
  __shared__ f16 lds[2][2][2][8192];   // [buf][A/B][half][16KB]

  const int tid = threadIdx.x;
  const int wid = tid >> 6, l = tid & 63;
  const int wr = wid >> 2, wc = wid & 3;

  // T1: bijective XCD swizzle (nwg % 8 == 0)
  const int nwg = gridDim.x;
  const int cpx = nwg >> 3;
  const int id = blockIdx.x;
  const int swz = (id & 7) * cpx + (id >> 3);
  const int by = swz % nby, bx = swz / nby;

  // staging source coords: physical LDS slot (j*512+tid)*16B -> logical (row,col)
  // via the inverse (== same, XOR involution) st_16x32 swizzle
  int r0s, c0s, r1s, c1s;
  {
    int rel = tid * 16;
    int sub = rel >> 10, q = rel & 1023;
    int inner = q ^ (((q >> 9) & 1) << 5);
    r0s = ((sub >> 1) << 4) + (inner >> 6);
    c0s = ((sub & 1) << 5) + ((inner & 63) >> 1);
    rel = (512 + tid) * 16;
    sub = rel >> 10; q = rel & 1023;
    inner = q ^ (((q >> 9) & 1) << 5);
    r1s = ((sub >> 1) << 4) + (inner >> 6);
    c1s = ((sub & 1) << 5) + ((inner & 63) >> 1);
  }
  const f16* pA0 = A + (size_t)(by * 256 + r0s) * K + c0s;
  const f16* pA1 = A + (size_t)(by * 256 + r1s) * K + c1s;
  const f16* pB0 = B + (size_t)(bx * 256 + r0s) * K + c0s;
  const f16* pB1 = B + (size_t)(bx * 256 + r1s) * K + c1s;

#define STAGE(bb, mat, h, t)                                                   \
  { const f16* g0 = (mat ? pB0 : pA0) + ((h) * 128) * K + (t) * 64;            \
    const f16* g1 = (mat ? pB1 : pA1) + ((h) * 128) * K + (t) * 64;            \
    gload16(g0, &lds[bb][mat][h][wid * 512]);                                  \
    gload16(g1, &lds[bb][mat][h][4096 + wid * 512]); }

  f16x8 af0[4][2], af1[4][2], bf[4][2];
  f32x4 acc[8][4] = {};

#define READ_A(DST, bufc, mh)                                                  \
  _Pragma("unroll") for (int mm = 0; mm < 4; ++mm)                             \
  _Pragma("unroll") for (int ks = 0; ks < 2; ++ks) {                           \
    int byt = (((((mh)*4 + mm) * 2) + ks) << 10) + ((l & 15) << 6) + ((l >> 4) << 4); \
    byt ^= ((l >> 3) & 1) << 5;                                                \
    DST[mm][ks] = *reinterpret_cast<const f16x8*>(                             \
        reinterpret_cast<const char*>(&lds[bufc][0][wr][0]) + byt);            \
  }
#define READ_B(bufc)                                                           \
  _Pragma("unroll") for (int n = 0; n < 4; ++n)                                \
  _Pragma("unroll") for (int ks = 0; ks < 2; ++ks) {                           \
    int byt = (((((wc & 1) * 4 + n) * 2) + ks) << 10) + ((l & 15) << 6) + ((l >> 4) << 4); \
    byt ^= ((l >> 3) & 1) << 5;                                                \
    bf[n][ks] = *reinterpret_cast<const f16x8*>(                               \
        reinterpret_cast<const char*>(&lds[bufc][1][wc >> 1][0]) + byt);       \
  }
#define CL(AF, mh, nh)                                                         \
  __builtin_amdgcn_s_setprio(1);                                               \
  _Pragma("unroll") for (int mm = 0; mm < 4; ++mm)                             \
  _Pragma("unroll") for (int nn = 0; nn < 2; ++nn)                             \
  _Pragma("unroll") for (int ks = 0; ks < 2; ++ks)                             \
    acc[(mh)*4 + mm][(nh)*2 + nn] =                                            \
        MFMA16(AF[mm][ks], bf[(nh)*2 + nn][ks], acc[(mh)*4 + mm][(nh)*2 + nn]);\
  __builtin_amdgcn_s_setprio(0);

  // prologue: tile0 all 4 halves, tile1 A-halves; wait tile0 landed (<=2 halves fly)
  STAGE(0, 0, 0, 0); STAGE(0, 0, 1, 0); STAGE(0, 1, 0, 0); STAGE(0, 1, 1, 0);
  STAGE(1, 0, 0, 1); STAGE(1, 0, 1, 1);
  VMWAIT(4);
  bar();

  for (int i = 0; i < NIT; ++i) {
    const int t1 = 2 * i + 1, t2 = 2 * i + 2, t3 = 2 * i + 3;
    const bool more = (i < NIT - 1);
    // ---- p1: read tile 2i (A-mh0 + all B) from buf0; stage (2i+1, B,h0) -> buf1
    READ_A(af0, 0, 0);
    READ_B(0);
    STAGE(1, 1, 0, t1);
    bar();
    CL(af0, 0, 0);
    bar();
    // ---- p2: read A-mh1; stage (2i+1, B,h1) -> buf1; drain reads before p3 stage
    READ_A(af1, 0, 1);
    STAGE(1, 1, 1, t1);
    bar();
    CL(af0, 0, 1);
    LGKM0();
    bar();
    // ---- p3: stage (2i+2, A,h0) -> buf0 (buf0 fully read+drained)
    if (more) STAGE(0, 0, 0, t2);
    bar();
    CL(af1, 1, 1);
    bar();
    // ---- p4: stage (2i+2, A,h1) -> buf0; counted vmcnt -> tile 2i+1 landed
    if (more) STAGE(0, 0, 1, t2);
    bar();
    CL(af1, 1, 0);
    if (i == NIT - 1) { VMWAIT(0); } else { VMWAIT(4); }
    bar();
    // ---- p5: read tile 2i+1 from buf1; stage (2i+2, B,h0) -> buf0
    READ_A(af0, 1, 0);
    READ_B(1);
    if (more) STAGE(0, 1, 0, t2);
    bar();
    CL(af0, 0, 0);
    bar();
    // ---- p6
    READ_A(af1, 1, 1);
    if (more) STAGE(0, 1, 1, t2);
    bar();
    CL(af0, 0, 1);
    LGKM0();
    bar();
    // ---- p7: stage (2i+3, A,h0) -> buf1
    if (more) STAGE(1, 0, 0, t3);
    bar();
    CL(af1, 1, 1);
    bar();
    // ---- p8: stage (2i+3, A,h1) -> buf1; counted vmcnt -> tile 2i+2 landed
    if (more) STAGE(1, 0, 1, t3);
    bar();
    CL(af1, 1, 0);
    VMWAIT(4);
    bar();
  }

  const int rr = by * 256 + wr * 128 + ((l >> 4) << 2);
  const int cc = bx * 256 + wc * 64 + (l & 15);
#pragma unroll
  for (int m = 0; m < 8; ++m)
#pragma unroll
    for (int n = 0; n < 4; ++n)
#pragma unroll
      for (int j = 0; j < 4; ++j)
        C[(size_t)(rr + m * 16 + j) * N + cc + n * 16] = (OutT)acc[m][n][j];
#undef STAGE
#undef READ_A
#undef READ_B
#undef CL
}

// ---------------- scores + softmax ----------------
__global__ __launch_bounds__(256, 2) void scores_softmax(const f16* __restrict__ qkv,
                                                         f16* __restrict__ zt) {
  const int bh = blockIdx.x;             // 0..127
  const int b = bh >> 4, h = bh & 15;
  const f16* qg = qkv + (size_t)b * 4096 * 3072 + h * 64;
  const f16* kg = qg + 1024;

  __shared__ f16 sQ[64 * 72];            // Qt[qd][y]
  __shared__ f16 sK[64 * 72];            // Kt[kd][y]
  __shared__ float sL[64 * 64];

  const int tid = threadIdx.x;
  const int w = tid >> 6, l = tid & 63;

  f32x4 acc[4] = {};

  for (int y0 = 0; y0 < 4096; y0 += 64) {
    __syncthreads();
#pragma unroll
    for (int cc = 0; cc < 2; ++cc) {
      const int c = 2 * w + cc;
      f16x8 vq = *reinterpret_cast<const f16x8*>(qg + (size_t)(y0 + l) * 3072 + c * 8);
      f16x8 vk = *reinterpret_cast<const f16x8*>(kg + (size_t)(y0 + l) * 3072 + c * 8);
#pragma unroll
      for (int j = 0; j < 8; ++j) {
        sQ[(c * 8 + j) * 72 + l] = vq[j];
        sK[(c * 8 + j) * 72 + l] = vk[j];
      }
    }
    __syncthreads();
#pragma unroll
    for (int ks = 0; ks < 2; ++ks) {
      f16x8 a = *reinterpret_cast<const f16x8*>(sK + (w * 16 + (l & 15)) * 72 + ks * 32 + ((l >> 4) << 3));
#pragma unroll
      for (int n = 0; n < 4; ++n) {
        f16x8 bq = *reinterpret_cast<const f16x8*>(sQ + (n * 16 + (l & 15)) * 72 + ks * 32 + ((l >> 4) << 3));
        acc[n] = MFMA16(a, bq, acc[n]);
      }
    }
  }

  __syncthreads();
#pragma unroll
  for (int n = 0; n < 4; ++n)
#pragma unroll
    for (int j = 0; j < 4; ++j)
      sL[(w * 16 + ((l >> 4) << 2) + j) * 64 + n * 16 + (l & 15)] = acc[n][j] * 0.125f;
  __syncthreads();

  if (tid < 64) {
    float mx = -1e30f;
    for (int q = 0; q < 64; ++q) mx = fmaxf(mx, sL[tid * 64 + q]);
    float s = 0.f;
    for (int q = 0; q < 64; ++q) {
      float e = __expf(sL[tid * 64 + q] - mx);
      sL[tid * 64 + q] = e;
      s += e;
    }
    float inv = 1.f / s;
    f16* dst = zt + (size_t)bh * 4096 + tid;
    for (int q = 0; q < 64; ++q) dst[q * 64] = (f16)(sL[tid * 64 + q] * inv);
  }
}

// ---------------- PV + head merge ----------------
__global__ __launch_bounds__(256, 2) void pv_merge(const f16* __restrict__ qkv,
                                                   const f16* __restrict__ zt,
                                                   f16* __restrict__ out2) {
  const int st = blockIdx.x;
  const int bh = blockIdx.y;
  const int b = bh >> 4, h = bh & 15;
  const f16* vg = qkv + (size_t)(b * 4096 + st * 128) * 3072 + 2048 + h * 64;

  __shared__ f16 sV[128 * 72];
  __shared__ f16 sZ[64 * 72];

  const int tid = threadIdx.x;
  const int w = tid >> 6, l = tid & 63;

#pragma unroll
  for (int p = 0; p < 4; ++p) {
    int idx = (p * 256 + tid) * 8;
    int row = idx >> 6, col = idx & 63;
    f16x8 v = *reinterpret_cast<const f16x8*>(vg + (size_t)row * 3072 + col);
    *reinterpret_cast<f16x8*>(sV + row * 72 + col) = v;
  }
#pragma unroll
  for (int p = 0; p < 2; ++p) {
    int idx = (p * 256 + tid) * 8;
    int row = idx >> 6, col = idx & 63;
    f16x8 v = *reinterpret_cast<const f16x8*>(zt + (size_t)bh * 4096 + idx);
    *reinterpret_cast<f16x8*>(sZ + row * 72 + col) = v;
  }
  __syncthreads();

  f32x4 acc[2][4] = {};
#pragma unroll
  for (int ks = 0; ks < 2; ++ks) {
    f16x8 av[2], bz[4];
#pragma unroll
    for (int m = 0; m < 2; ++m)
      av[m] = *reinterpret_cast<const f16x8*>(sV + (w * 32 + m * 16 + (l & 15)) * 72 + ks * 32 + ((l >> 4) << 3));
#pragma unroll
    for (int n = 0; n < 4; ++n)
      bz[n] = *reinterpret_cast<const f16x8*>(sZ + (n * 16 + (l & 15)) * 72 + ks * 32 + ((l >> 4) << 3));
#pragma unroll
    for (int m = 0; m < 2; ++m)
#pragma unroll
      for (int n = 0; n < 4; ++n)
        acc[m][n] = MFMA16(av[m], bz[n], acc[m][n]);
  }

#pragma unroll
  for (int m = 0; m < 2; ++m)
#pragma unroll
    for (int n = 0; n < 4; ++n)
#pragma unroll
      for (int j = 0; j < 4; ++j) {
        int s = st * 128 + w * 32 + m * 16 + ((l >> 4) << 2) + j;
        out2[(size_t)(b * 4096 + s) * 1024 + h * 64 + n * 16 + (l & 15)] = (f16)acc[m][n][j];
      }
}

// ---------------- launch ----------------
extern "C" void kernel_launch(void* const* d_in, const int* in_sizes, int n_in,
                              void* d_out, int out_size, void* d_ws, size_t ws_size,
                              hipStream_t stream) {
  const float* x  = (const float*)d_in[0];
  const float* Wq = (const float*)d_in[1];
  const float* Wk = (const float*)d_in[2];
  const float* Wv = (const float*)d_in[3];
  const float* Wo = (const float*)d_in[4];
  float* out = (float*)d_out;

  f16* xh    = (f16*)d_ws;               //  33,554,432  x (f16)
  f16* qkvh  = xh + 33554432;            // 100,663,296  [32768 x 3072] q|k|v
  f16* wqkvh = qkvh + 100663296;         //   3,145,728  [3072 x 1024]
  f16* woh   = wqkvh + 3145728;          //   1,048,576  [1024 x 1024]
  f16* zth   = woh + 1048576;            //     524,288  [128][64 zq][64 kd]
  f16* out2h = zth + 524288;             //  33,554,432  [32768 x 1024] merged

  cast_f32_to_f16<<<32768, 256, 0, stream>>>(x, xh, 33554432 / 4);
  cast_f32_to_f16<<<1024, 256, 0, stream>>>(Wq, wqkvh, 1048576 / 4);
  cast_f32_to_f16<<<1024, 256, 0, stream>>>(Wk, wqkvh + 1048576, 1048576 / 4);
  cast_f32_to_f16<<<1024, 256, 0, stream>>>(Wv, wqkvh + 2097152, 1048576 / 4);
  cast_f32_to_f16<<<1024, 256, 0, stream>>>(Wo, woh, 1048576 / 4);

  // QKV projection: [32768,3072] = xh * Wqkv^T   (1536 blocks, %8==0)
  gemm_bt_8ph<f16><<<128 * 12, 512, 0, stream>>>(xh, wqkvh, qkvh, 3072, 128);

  scores_softmax<<<128, 256, 0, stream>>>(qkvh, zth);
  pv_merge<<<dim3(32, 128), 256, 0, stream>>>(qkvh, zth, out2h);

  // output projection: d_out = out2 * Wo^T (f32 out)   (512 blocks, %8==0)
  gemm_bt_8ph<float><<<128 * 4, 512, 0, stream>>>(out2h, woh, out, 1024, 128);
}

// Round 3
// 502.243 us; speedup vs baseline: 1.5791x; 1.5791x over previous
//
#include <hip/hip_runtime.h>
#include <hip/hip_fp16.h>

typedef _Float16 f16;
typedef _Float16 f16x8 __attribute__((ext_vector_type(8)));
typedef _Float16 f16x4 __attribute__((ext_vector_type(4)));
typedef float    f32x4 __attribute__((ext_vector_type(4)));

#define MFMA16(a, b, c) __builtin_amdgcn_mfma_f32_16x16x32_f16((a), (b), (c), 0, 0, 0)

__device__ __forceinline__ void gload16(const void* g, void* l) {
  __builtin_amdgcn_global_load_lds(
      (const __attribute__((address_space(1))) unsigned int*)g,
      (__attribute__((address_space(3))) unsigned int*)l,
      16, 0, 0);
}

__device__ __forceinline__ void bar() {
  asm volatile("" ::: "memory");
  __builtin_amdgcn_s_barrier();
  asm volatile("" ::: "memory");
}
#define VMWAIT(n) asm volatile("s_waitcnt vmcnt(" #n ")" ::: "memory")

// ---------------- f32 -> f16 cast ----------------
__global__ __launch_bounds__(256) void cast_f32_to_f16(const float* __restrict__ src,
                                                       f16* __restrict__ dst, int n4) {
  int i = blockIdx.x * 256 + threadIdx.x;
  if (i >= n4) return;
  float4 v = reinterpret_cast<const float4*>(src)[i];
  f16x4 o = { (f16)v.x, (f16)v.y, (f16)v.z, (f16)v.w };
  reinterpret_cast<f16x4*>(dst)[i] = o;
}

// ============ 256x256 8-phase GEMM: C[M,N] = A[M,K] * B[N,K]^T, K=1024 ============
// 512 threads = 8 waves (2M x 4N), per-wave 128x64 output. BK=64, double-buffered
// 128 KiB LDS, st_16x32 XOR swizzle, counted vmcnt, setprio MFMA.
// launch_bounds(512,1): block needs 2 waves/SIMD -> 256-VGPR cap, ~220 live, no spill.
template <typename OutT>
__global__ __launch_bounds__(512, 1) void gemm_bt_8ph(const f16* __restrict__ A,
                                                      const f16* __restrict__ B,
                                                      OutT* __restrict__ C,
                                                      int N, int nby) {
  constexpr int K = 1024;
  constexpr int T = K / 64;     // 16 K-tiles
  constexpr int NIT = T / 2;    // 8 iterations
  __shared__ f16 lds[2][2][2][8192];   // [buf][A/B][half][16KB]

  const int tid = threadIdx.x;
  const int wid = tid >> 6, l = tid & 63;
  const int wr = wid >> 2, wc = wid & 3;

  // T1: bijective XCD swizzle (nwg % 8 == 0)
  const int nwg = gridDim.x;
  const int cpx = nwg >> 3;
  const int id = blockIdx.x;
  const int swz = (id & 7) * cpx + (id >> 3);
  const int by = swz % nby, bx = swz / nby;

  // staging source coords: physical LDS slot (j*512+tid)*16B -> logical (row,col)
  // via the inverse (== same, XOR involution) st_16x32 swizzle
  int r0s, c0s, r1s, c1s;
  {
    int rel = tid * 16;
    int sub = rel >> 10, q = rel & 1023;
    int inner = q ^ (((q >> 9) & 1) << 5);
    r0s = ((sub >> 1) << 4) + (inner >> 6);
    c0s = ((sub & 1) << 5) + ((inner & 63) >> 1);
    rel = (512 + tid) * 16;
    sub = rel >> 10; q = rel & 1023;
    inner = q ^ (((q >> 9) & 1) << 5);
    r1s = ((sub >> 1) << 4) + (inner >> 6);
    c1s = ((sub & 1) << 5) + ((inner & 63) >> 1);
  }
  const f16* pA0 = A + (size_t)(by * 256 + r0s) * K + c0s;
  const f16* pA1 = A + (size_t)(by * 256 + r1s) * K + c1s;
  const f16* pB0 = B + (size_t)(bx * 256 + r0s) * K + c0s;
  const f16* pB1 = B + (size_t)(bx * 256 + r1s) * K + c1s;

#define STAGE(bb, mat, h, t)                                                   \
  { const f16* g0 = (mat ? pB0 : pA0) + ((h) * 128) * K + (t) * 64;            \
    const f16* g1 = (mat ? pB1 : pA1) + ((h) * 128) * K + (t) * 64;            \
    gload16(g0, &lds[bb][mat][h][wid * 512]);                                  \
    gload16(g1, &lds[bb][mat][h][4096 + wid * 512]); }

  f16x8 af0[4][2], af1[4][2], bf0[2][2], bf1[2][2];
  f32x4 acc[8][4] = {};

  // read A m-half `mh` of buffer `bufc` into DST[4][2]
#define READ_A_MH(DST, bufc, mh)                                               \
  _Pragma("unroll") for (int mm = 0; mm < 4; ++mm)                             \
  _Pragma("unroll") for (int ks = 0; ks < 2; ++ks) {                           \
    int byt = (((((mh)*4 + mm) * 2) + ks) << 10) + ((l & 15) << 6) + ((l >> 4) << 4); \
    byt ^= ((l >> 3) & 1) << 5;                                                \
    DST[mm][ks] = *reinterpret_cast<const f16x8*>(                             \
        reinterpret_cast<const char*>(&lds[bufc][0][wr][0]) + byt);            \
  }
  // read B n-half `nh` (global n = nh*2+nn) into DST[2][2]
#define READ_B_NH(DST, bufc, nh)                                               \
  _Pragma("unroll") for (int nn = 0; nn < 2; ++nn)                             \
  _Pragma("unroll") for (int ks = 0; ks < 2; ++ks) {                           \
    int byt = (((((wc & 1) * 4 + (nh)*2 + nn) * 2) + ks) << 10) + ((l & 15) << 6) + ((l >> 4) << 4); \
    byt ^= ((l >> 3) & 1) << 5;                                                \
    DST[nn][ks] = *reinterpret_cast<const f16x8*>(                             \
        reinterpret_cast<const char*>(&lds[bufc][1][wc >> 1][0]) + byt);       \
  }
  // 16-MFMA cluster: C-quadrant (mh, nh)
#define CL2(AF, BF, mh, nh)                                                    \
  __builtin_amdgcn_s_setprio(1);                                               \
  _Pragma("unroll") for (int mm = 0; mm < 4; ++mm)                             \
  _Pragma("unroll") for (int nn = 0; nn < 2; ++nn)                             \
  _Pragma("unroll") for (int ks = 0; ks < 2; ++ks)                             \
    acc[(mh)*4 + mm][(nh)*2 + nn] =                                            \
        MFMA16(AF[mm][ks], BF[nn][ks], acc[(mh)*4 + mm][(nh)*2 + nn]);         \
  __builtin_amdgcn_s_setprio(0);

  // prologue: tile0 all 4 halves -> buf0, tile1 A halves -> buf1
  STAGE(0, 0, 0, 0); STAGE(0, 0, 1, 0); STAGE(0, 1, 0, 0); STAGE(0, 1, 1, 0);
  STAGE(1, 0, 0, 1); STAGE(1, 0, 1, 1);
  VMWAIT(4);          // tile0's 8 loads landed; tile1-A (4) in flight
  bar();

  for (int i = 0; i < NIT; ++i) {
    const int t1 = 2 * i + 1, t2 = 2 * i + 2, t3 = 2 * i + 3;
    const bool more = (i < NIT - 1);
    // p1: quadrant (mh0,nh0) of tile 2i; stage t1-Bh0 -> buf1
    READ_A_MH(af0, 0, 0); READ_B_NH(bf0, 0, 0);
    STAGE(1, 1, 0, t1);
    bar(); CL2(af0, bf0, 0, 0); bar();
    // p2: (mh0,nh1); stage t1-Bh1 -> buf1
    READ_B_NH(bf1, 0, 1);
    STAGE(1, 1, 1, t1);
    bar(); CL2(af0, bf1, 0, 1); bar();
    // p3: (mh1,nh1)  [no stage]
    READ_A_MH(af1, 0, 1);
    bar(); CL2(af1, bf1, 1, 1); bar();
    // p4: (mh1,nh0); stage t2-Bh0 -> buf0-B (reads done p2); wait tile t1 landed
    if (more) STAGE(0, 1, 0, t2);
    bar(); CL2(af1, bf0, 1, 0);
    if (more) { VMWAIT(2); } else { VMWAIT(0); }
    bar();
    // p5: tile 2i+1 (mh0,nh0) from buf1; stage t2-Ah0 -> buf0-A (reads done p3)
    READ_A_MH(af0, 1, 0); READ_B_NH(bf0, 1, 0);
    if (more) STAGE(0, 0, 0, t2);
    bar(); CL2(af0, bf0, 0, 0); bar();
    // p6: (mh0,nh1); stage t2-Ah1 -> buf0
    READ_B_NH(bf1, 1, 1);
    if (more) STAGE(0, 0, 1, t2);
    bar(); CL2(af0, bf1, 0, 1); bar();
    // p7: (mh1,nh1); stage t2-Bh1 -> buf0
    READ_A_MH(af1, 1, 1);
    if (more) STAGE(0, 1, 1, t2);
    bar(); CL2(af1, bf1, 1, 1); bar();
    // p8: (mh1,nh0); stage t3-A (both halves) -> buf1-A (reads done p7); wait t2 landed
    if (more) { STAGE(1, 0, 0, t3); STAGE(1, 0, 1, t3); }
    bar(); CL2(af1, bf0, 1, 0);
    if (more) VMWAIT(4);
    bar();
  }

  const int rr = by * 256 + wr * 128 + ((l >> 4) << 2);
  const int cc = bx * 256 + wc * 64 + (l & 15);
#pragma unroll
  for (int m = 0; m < 8; ++m)
#pragma unroll
    for (int n = 0; n < 4; ++n)
#pragma unroll
      for (int j = 0; j < 4; ++j)
        C[(size_t)(rr + m * 16 + j) * N + cc + n * 16] = (OutT)acc[m][n][j];
#undef STAGE
#undef READ_A_MH
#undef READ_B_NH
#undef CL2
}

// ---------------- scores + softmax ----------------
__global__ __launch_bounds__(256, 2) void scores_softmax(const f16* __restrict__ qkv,
                                                         f16* __restrict__ zt) {
  const int bh = blockIdx.x;             // 0..127
  const int b = bh >> 4, h = bh & 15;
  const f16* qg = qkv + (size_t)b * 4096 * 3072 + h * 64;
  const f16* kg = qg + 1024;

  __shared__ f16 sQ[64 * 72];            // Qt[qd][y]
  __shared__ f16 sK[64 * 72];            // Kt[kd][y]
  __shared__ float sL[64 * 64];

  const int tid = threadIdx.x;
  const int w = tid >> 6, l = tid & 63;

  f32x4 acc[4] = {};

  for (int y0 = 0; y0 < 4096; y0 += 64) {
    __syncthreads();
#pragma unroll
    for (int cc = 0; cc < 2; ++cc) {
      const int c = 2 * w + cc;
      f16x8 vq = *reinterpret_cast<const f16x8*>(qg + (size_t)(y0 + l) * 3072 + c * 8);
      f16x8 vk = *reinterpret_cast<const f16x8*>(kg + (size_t)(y0 + l) * 3072 + c * 8);
#pragma unroll
      for (int j = 0; j < 8; ++j) {
        sQ[(c * 8 + j) * 72 + l] = vq[j];
        sK[(c * 8 + j) * 72 + l] = vk[j];
      }
    }
    __syncthreads();
#pragma unroll
    for (int ks = 0; ks < 2; ++ks) {
      f16x8 a = *reinterpret_cast<const f16x8*>(sK + (w * 16 + (l & 15)) * 72 + ks * 32 + ((l >> 4) << 3));
#pragma unroll
      for (int n = 0; n < 4; ++n) {
        f16x8 bq = *reinterpret_cast<const f16x8*>(sQ + (n * 16 + (l & 15)) * 72 + ks * 32 + ((l >> 4) << 3));
        acc[n] = MFMA16(a, bq, acc[n]);
      }
    }
  }

  __syncthreads();
#pragma unroll
  for (int n = 0; n < 4; ++n)
#pragma unroll
    for (int j = 0; j < 4; ++j)
      sL[(w * 16 + ((l >> 4) << 2) + j) * 64 + n * 16 + (l & 15)] = acc[n][j] * 0.125f;
  __syncthreads();

  if (tid < 64) {
    float mx = -1e30f;
    for (int q = 0; q < 64; ++q) mx = fmaxf(mx, sL[tid * 64 + q]);
    float s = 0.f;
    for (int q = 0; q < 64; ++q) {
      float e = __expf(sL[tid * 64 + q] - mx);
      sL[tid * 64 + q] = e;
      s += e;
    }
    float inv = 1.f / s;
    f16* dst = zt + (size_t)bh * 4096 + tid;
    for (int q = 0; q < 64; ++q) dst[q * 64] = (f16)(sL[tid * 64 + q] * inv);
  }
}

// ---------------- PV + head merge ----------------
__global__ __launch_bounds__(256, 2) void pv_merge(const f16* __restrict__ qkv,
                                                   const f16* __restrict__ zt,
                                                   f16* __restrict__ out2) {
  const int st = blockIdx.x;
  const int bh = blockIdx.y;
  const int b = bh >> 4, h = bh & 15;
  const f16* vg = qkv + (size_t)(b * 4096 + st * 128) * 3072 + 2048 + h * 64;

  __shared__ f16 sV[128 * 72];
  __shared__ f16 sZ[64 * 72];

  const int tid = threadIdx.x;
  const int w = tid >> 6, l = tid & 63;

#pragma unroll
  for (int p = 0; p < 4; ++p) {
    int idx = (p * 256 + tid) * 8;
    int row = idx >> 6, col = idx & 63;
    f16x8 v = *reinterpret_cast<const f16x8*>(vg + (size_t)row * 3072 + col);
    *reinterpret_cast<f16x8*>(sV + row * 72 + col) = v;
  }
#pragma unroll
  for (int p = 0; p < 2; ++p) {
    int idx = (p * 256 + tid) * 8;
    int row = idx >> 6, col = idx & 63;
    f16x8 v = *reinterpret_cast<const f16x8*>(zt + (size_t)bh * 4096 + idx);
    *reinterpret_cast<f16x8*>(sZ + row * 72 + col) = v;
  }
  __syncthreads();

  f32x4 acc[2][4] = {};
#pragma unroll
  for (int ks = 0; ks < 2; ++ks) {
    f16x8 av[2], bz[4];
#pragma unroll
    for (int m = 0; m < 2; ++m)
      av[m] = *reinterpret_cast<const f16x8*>(sV + (w * 32 + m * 16 + (l & 15)) * 72 + ks * 32 + ((l >> 4) << 3));
#pragma unroll
    for (int n = 0; n < 4; ++n)
      bz[n] = *reinterpret_cast<const f16x8*>(sZ + (n * 16 + (l & 15)) * 72 + ks * 32 + ((l >> 4) << 3));
#pragma unroll
    for (int m = 0; m < 2; ++m)
#pragma unroll
      for (int n = 0; n < 4; ++n)
        acc[m][n] = MFMA16(av[m], bz[n], acc[m][n]);
  }

#pragma unroll
  for (int m = 0; m < 2; ++m)
#pragma unroll
    for (int n = 0; n < 4; ++n)
#pragma unroll
      for (int j = 0; j < 4; ++j) {
        int s = st * 128 + w * 32 + m * 16 + ((l >> 4) << 2) + j;
        out2[(size_t)(b * 4096 + s) * 1024 + h * 64 + n * 16 + (l & 15)] = (f16)acc[m][n][j];
      }
}

// ---------------- launch ----------------
extern "C" void kernel_launch(void* const* d_in, const int* in_sizes, int n_in,
                              void* d_out, int out_size, void* d_ws, size_t ws_size,
                              hipStream_t stream) {
  const float* x  = (const float*)d_in[0];
  const float* Wq = (const float*)d_in[1];
  const float* Wk = (const float*)d_in[2];
  const float* Wv = (const float*)d_in[3];
  const float* Wo = (const float*)d_in[4];
  float* out = (float*)d_out;

  f16* xh    = (f16*)d_ws;               //  33,554,432  x (f16)
  f16* qkvh  = xh + 33554432;            // 100,663,296  [32768 x 3072] q|k|v
  f16* wqkvh = qkvh + 100663296;         //   3,145,728  [3072 x 1024]
  f16* woh   = wqkvh + 3145728;          //   1,048,576  [1024 x 1024]
  f16* zth   = woh + 1048576;            //     524,288  [128][64 zq][64 kd]
  f16* out2h = zth + 524288;             //  33,554,432  [32768 x 1024] merged

  cast_f32_to_f16<<<32768, 256, 0, stream>>>(x, xh, 33554432 / 4);
  cast_f32_to_f16<<<1024, 256, 0, stream>>>(Wq, wqkvh, 1048576 / 4);
  cast_f32_to_f16<<<1024, 256, 0, stream>>>(Wk, wqkvh + 1048576, 1048576 / 4);
  cast_f32_to_f16<<<1024, 256, 0, stream>>>(Wv, wqkvh + 2097152, 1048576 / 4);
  cast_f32_to_f16<<<1024, 256, 0, stream>>>(Wo, woh, 1048576 / 4);

  // QKV projection: [32768,3072] = xh * Wqkv^T   (1536 blocks, %8==0)
  gemm_bt_8ph<f16><<<128 * 12, 512, 0, stream>>>(xh, wqkvh, qkvh, 3072, 128);

  scores_softmax<<<128, 256, 0, stream>>>(qkvh, zth);
  pv_merge<<<dim3(32, 128), 256, 0, stream>>>(qkvh, zth, out2h);

  // output projection: d_out = out2 * Wo^T (f32 out)   (512 blocks, %8==0)
  gemm_bt_8ph<float><<<128 * 4, 512, 0, stream>>>(out2h, woh, out, 1024, 128);
}

// Round 5
// 491.726 us; speedup vs baseline: 1.6129x; 1.0214x over previous
//
#include <hip/hip_runtime.h>
#include <hip/hip_fp16.h>

typedef _Float16 f16;
typedef _Float16 f16x8 __attribute__((ext_vector_type(8)));
typedef _Float16 f16x4 __attribute__((ext_vector_type(4)));
typedef float    f32x4 __attribute__((ext_vector_type(4)));

#define MFMA16(a, b, c) __builtin_amdgcn_mfma_f32_16x16x32_f16((a), (b), (c), 0, 0, 0)

__device__ __forceinline__ void bar() {
  asm volatile("" ::: "memory");
  __builtin_amdgcn_s_barrier();
  asm volatile("" ::: "memory");
}
#define VMW2() asm volatile("s_waitcnt vmcnt(2)" ::: "memory")
#define VMW0() asm volatile("s_waitcnt vmcnt(0)" ::: "memory")
#define SB0()  __builtin_amdgcn_sched_barrier(0)

// global->LDS async, 16B/lane. Offset arg MUST be 0: the imm offset applies to
// BOTH global and LDS address (R4 bug) — all offsets go through the pointer.
#define GLOAD16(P, L)                                                          \
  __builtin_amdgcn_global_load_lds(                                            \
      (const __attribute__((address_space(1))) unsigned int*)(P),              \
      (__attribute__((address_space(3))) unsigned int*)(L), 16, 0, 0)

// ---------------- f32 -> f16 cast ----------------
__global__ __launch_bounds__(256) void cast_f32_to_f16(const float* __restrict__ src,
                                                       f16* __restrict__ dst, int n4) {
  int i = blockIdx.x * 256 + threadIdx.x;
  if (i >= n4) return;
  float4 v = reinterpret_cast<const float4*>(src)[i];
  f16x4 o = { (f16)v.x, (f16)v.y, (f16)v.z, (f16)v.w };
  reinterpret_cast<f16x4*>(dst)[i] = o;
}

// ============ 256x256 pipelined GEMM: C[M,N] = A[M,K] * B[N,K]^T, K=1024 ============
// 512 threads = 8 waves (2M x 4N), per-wave 128x64. BK=64, 2-buf 128 KiB LDS,
// st_16x32 swizzle. 4 phases/tile; ds_reads issued ONE PHASE AHEAD of their MFMA
// cluster (overlap LDS drain with MFMA exec); stages 1 half-tile/phase (A one tile
// ahead, B two); single counted VMWAIT(2) gate per tile at p2.
template <typename OutT>
__global__ __launch_bounds__(512, 1) void gemm_bt_8ph(const f16* __restrict__ A,
                                                      const f16* __restrict__ B,
                                                      OutT* __restrict__ C,
                                                      int N, int nby) {
  constexpr int K = 1024;
  __shared__ f16 lds[2][2][2][8192];   // [buf][A/B][half][16KB]

  const int tid = threadIdx.x;
  const int wid = tid >> 6, l = tid & 63;
  const int wr = wid >> 2, wc = wid & 3;

  // T1: bijective XCD swizzle (nwg % 8 == 0)
  const int nwg = gridDim.x;
  const int cpx = nwg >> 3;
  const int id = blockIdx.x;
  const int swz = (id & 7) * cpx + (id >> 3);
  const int by = swz % nby, bx = swz / nby;

  // staging source coords: physical LDS slot (j*512+tid)*16B -> logical (row,col)
  // via the inverse (== same, XOR involution) st_16x32 swizzle
  int r0s, c0s, r1s, c1s;
  {
    int rel = tid * 16;
    int sub = rel >> 10, q = rel & 1023;
    int inner = q ^ (((q >> 9) & 1) << 5);
    r0s = ((sub >> 1) << 4) + (inner >> 6);
    c0s = ((sub & 1) << 5) + ((inner & 63) >> 1);
    rel = (512 + tid) * 16;
    sub = rel >> 10; q = rel & 1023;
    inner = q ^ (((q >> 9) & 1) << 5);
    r1s = ((sub >> 1) << 4) + (inner >> 6);
    c1s = ((sub & 1) << 5) + ((inner & 63) >> 1);
  }
  // loop-carried staging pointers; after prologue they sit at tile T+1
  const f16* gA0a = A + (size_t)(by * 256 + r0s) * K + c0s;
  const f16* gA0b = A + (size_t)(by * 256 + r1s) * K + c1s;
  const f16* gA1a = gA0a + 128 * K;
  const f16* gA1b = gA0b + 128 * K;
  const f16* gB0a = B + (size_t)(bx * 256 + r0s) * K + c0s;
  const f16* gB0b = B + (size_t)(bx * 256 + r1s) * K + c1s;
  const f16* gB1a = gB0a + 128 * K;
  const f16* gB1b = gB0b + 128 * K;

#define STAGE_P(G0, G1, EOFF, LB, MAT, H)                                      \
  { GLOAD16((G0) + (EOFF), &lds[LB][MAT][H][wid * 512]);                       \
    GLOAD16((G1) + (EOFF), &lds[LB][MAT][H][4096 + wid * 512]); }

  // hoisted lane-dependent swizzled read base (bytes within a [128][64] region)
  const int lane_rd = (((l & 15) << 6) + ((l >> 4) << 4)) ^ (((l >> 3) & 1) << 5);
  const char* rdA0 = (const char*)&lds[0][0][wr][0] + lane_rd;
  const char* rdA1 = (const char*)&lds[1][0][wr][0] + lane_rd;
  const char* rdB0 = (const char*)&lds[0][1][wc >> 1][0] + (wc & 1) * 8192 + lane_rd;
  const char* rdB1 = (const char*)&lds[1][1][wc >> 1][0] + (wc & 1) * 8192 + lane_rd;

  f16x8 afA[4][2], afB[4][2], bf0X[2][2], bf0Y[2][2], bf1[2][2];
  f32x4 acc[8][4] = {};

#define READ_A_MH(DST, RD, mh)                                                 \
  _Pragma("unroll") for (int mm = 0; mm < 4; ++mm)                             \
  _Pragma("unroll") for (int ks = 0; ks < 2; ++ks)                             \
    DST[mm][ks] = *reinterpret_cast<const f16x8*>(                             \
        (RD) + (((((mh)*4 + mm) * 2) + ks) << 10));
#define READ_B_NH(DST, RD, nh)                                                 \
  _Pragma("unroll") for (int nn = 0; nn < 2; ++nn)                             \
  _Pragma("unroll") for (int ks = 0; ks < 2; ++ks)                             \
    DST[nn][ks] = *reinterpret_cast<const f16x8*>(                             \
        (RD) + (((((nh)*2 + nn) * 2) + ks) << 10));
#define CL2(AF, BF, mh, nh)                                                    \
  __builtin_amdgcn_s_setprio(1);                                               \
  _Pragma("unroll") for (int mm = 0; mm < 4; ++mm)                             \
  _Pragma("unroll") for (int nn = 0; nn < 2; ++nn)                             \
  _Pragma("unroll") for (int ks = 0; ks < 2; ++ks)                             \
    acc[(mh)*4 + mm][(nh)*2 + nn] =                                            \
        MFMA16(AF[mm][ks], BF[nn][ks], acc[(mh)*4 + mm][(nh)*2 + nn]);         \
  __builtin_amdgcn_s_setprio(0);

  // Per-tile body. LB = buf of tile T, LBN = other buf (tile T+1).
  // p0: rd bf1        | stage (T+1).Ah0 -> LBN | CL2 q0=(0,0) af_mh0,bf0cur
  // p1: rd afB(mh1)   | stage (T+1).Ah1 -> LBN | CL2 q1=(0,1) af_mh0,bf1
  // p2:               | stage (T+2).Bh0 -> LB  | VMW(2) gate | CL2 q2=(1,1)
  // p3: rd T+1.q0     | stage (T+2).Bh1 -> LB  | CL2 q3=(1,0) afB,bf0cur
#define TILE(LB, LBN, RDA_C, RDA_N, RDB_C, RDB_N, BF0C, BF0N, SA, SB, W2, W0, RDN) \
  READ_B_NH(bf1, RDB_C, 1);                                                    \
  if (SA) STAGE_P(gA0a, gA0b, 0, LBN, 0, 0);                                   \
  SB0();                                                                       \
  CL2(afA, BF0C, 0, 0);                                                        \
  bar();                                                                       \
  READ_A_MH(afB, RDA_C, 1);                                                    \
  if (SA) STAGE_P(gA1a, gA1b, 0, LBN, 0, 1);                                   \
  SB0();                                                                       \
  CL2(afA, bf1, 0, 1);                                                         \
  bar();                                                                       \
  if (SB) STAGE_P(gB0a, gB0b, 64, LB, 1, 0);                                   \
  if (W2) VMW2();                                                              \
  if (W0) VMW0();                                                              \
  SB0();                                                                       \
  CL2(afB, bf1, 1, 1);                                                         \
  bar();                                                                       \
  if (RDN) { READ_A_MH(afA, RDA_N, 0); READ_B_NH(BF0N, RDB_N, 0); }            \
  if (SB) STAGE_P(gB1a, gB1b, 64, LB, 1, 1);                                   \
  SB0();                                                                       \
  CL2(afB, BF0C, 1, 0);                                                        \
  bar();                                                                       \
  gA0a += 64; gA0b += 64; gA1a += 64; gA1b += 64;                              \
  gB0a += 64; gB0b += 64; gB1a += 64; gB1b += 64;

  // ---- prologue: t0.B, t0.A, t1.Bh0 | W(2) | bar | reads t0.q0 + t1.Bh1 | bar
  STAGE_P(gB0a, gB0b, 0, 0, 1, 0);   // t0.Bh0 -> buf0
  STAGE_P(gB1a, gB1b, 0, 0, 1, 1);   // t0.Bh1
  STAGE_P(gA0a, gA0b, 0, 0, 0, 0);   // t0.Ah0
  STAGE_P(gA1a, gA1b, 0, 0, 0, 1);   // t0.Ah1
  STAGE_P(gB0a, gB0b, 64, 1, 1, 0);  // t1.Bh0 -> buf1
  VMW2();                            // t0 landed; t1.Bh0 in flight
  bar();
  READ_A_MH(afA, rdA0, 0);           // t0.q0 operands
  READ_B_NH(bf0X, rdB0, 0);
  STAGE_P(gB1a, gB1b, 64, 1, 1, 1);  // t1.Bh1 -> buf1
  bar();
  gA0a += 64; gA0b += 64; gA1a += 64; gA1b += 64;
  gB0a += 64; gB0b += 64; gB1a += 64; gB1b += 64;   // ptrs now at t1

  // ---- steady: tiles 0..13 (7 even/odd pairs, all stages on)
  for (int t = 0; t < 14; t += 2) {
    TILE(0, 1, rdA0, rdA1, rdB0, rdB1, bf0X, bf0Y, 1, 1, 1, 0, 1)
    TILE(1, 0, rdA1, rdA0, rdB1, rdB0, bf0Y, bf0X, 1, 1, 1, 0, 1)
  }
  // ---- tail: t14 (stage t15.A only, drain gate), t15 (no stages, no read-ahead)
  TILE(0, 1, rdA0, rdA1, rdB0, rdB1, bf0X, bf0Y, 1, 0, 0, 1, 1)
  TILE(1, 0, rdA1, rdA0, rdB1, rdB0, bf0Y, bf0X, 0, 0, 0, 0, 0)

  const int rr = by * 256 + wr * 128 + ((l >> 4) << 2);
  const int cc = bx * 256 + wc * 64 + (l & 15);
#pragma unroll
  for (int m = 0; m < 8; ++m)
#pragma unroll
    for (int n = 0; n < 4; ++n)
#pragma unroll
      for (int j = 0; j < 4; ++j)
        C[(size_t)(rr + m * 16 + j) * N + cc + n * 16] = (OutT)acc[m][n][j];
#undef STAGE_P
#undef READ_A_MH
#undef READ_B_NH
#undef CL2
#undef TILE
}

// ---------------- scores + softmax ----------------
__global__ __launch_bounds__(256, 2) void scores_softmax(const f16* __restrict__ qkv,
                                                         f16* __restrict__ zt) {
  const int bh = blockIdx.x;             // 0..127
  const int b = bh >> 4, h = bh & 15;
  const f16* qg = qkv + (size_t)b * 4096 * 3072 + h * 64;
  const f16* kg = qg + 1024;

  __shared__ f16 sQ[64 * 72];            // Qt[qd][y]
  __shared__ f16 sK[64 * 72];            // Kt[kd][y]
  __shared__ float sL[64 * 64];

  const int tid = threadIdx.x;
  const int w = tid >> 6, l = tid & 63;

  f32x4 acc[4] = {};

  for (int y0 = 0; y0 < 4096; y0 += 64) {
    __syncthreads();
#pragma unroll
    for (int cc = 0; cc < 2; ++cc) {
      const int c = 2 * w + cc;
      f16x8 vq = *reinterpret_cast<const f16x8*>(qg + (size_t)(y0 + l) * 3072 + c * 8);
      f16x8 vk = *reinterpret_cast<const f16x8*>(kg + (size_t)(y0 + l) * 3072 + c * 8);
#pragma unroll
      for (int j = 0; j < 8; ++j) {
        sQ[(c * 8 + j) * 72 + l] = vq[j];
        sK[(c * 8 + j) * 72 + l] = vk[j];
      }
    }
    __syncthreads();
#pragma unroll
    for (int ks = 0; ks < 2; ++ks) {
      f16x8 a = *reinterpret_cast<const f16x8*>(sK + (w * 16 + (l & 15)) * 72 + ks * 32 + ((l >> 4) << 3));
#pragma unroll
      for (int n = 0; n < 4; ++n) {
        f16x8 bq = *reinterpret_cast<const f16x8*>(sQ + (n * 16 + (l & 15)) * 72 + ks * 32 + ((l >> 4) << 3));
        acc[n] = MFMA16(a, bq, acc[n]);
      }
    }
  }

  __syncthreads();
#pragma unroll
  for (int n = 0; n < 4; ++n)
#pragma unroll
    for (int j = 0; j < 4; ++j)
      sL[(w * 16 + ((l >> 4) << 2) + j) * 64 + n * 16 + (l & 15)] = acc[n][j] * 0.125f;
  __syncthreads();

  if (tid < 64) {
    float mx = -1e30f;
    for (int q = 0; q < 64; ++q) mx = fmaxf(mx, sL[tid * 64 + q]);
    float s = 0.f;
    for (int q = 0; q < 64; ++q) {
      float e = __expf(sL[tid * 64 + q] - mx);
      sL[tid * 64 + q] = e;
      s += e;
    }
    float inv = 1.f / s;
    f16* dst = zt + (size_t)bh * 4096 + tid;
    for (int q = 0; q < 64; ++q) dst[q * 64] = (f16)(sL[tid * 64 + q] * inv);
  }
}

// ---------------- PV + head merge ----------------
__global__ __launch_bounds__(256, 2) void pv_merge(const f16* __restrict__ qkv,
                                                   const f16* __restrict__ zt,
                                                   f16* __restrict__ out2) {
  const int st = blockIdx.x;
  const int bh = blockIdx.y;
  const int b = bh >> 4, h = bh & 15;
  const f16* vg = qkv + (size_t)(b * 4096 + st * 128) * 3072 + 2048 + h * 64;

  __shared__ f16 sV[128 * 72];
  __shared__ f16 sZ[64 * 72];

  const int tid = threadIdx.x;
  const int w = tid >> 6, l = tid & 63;

#pragma unroll
  for (int p = 0; p < 4; ++p) {
    int idx = (p * 256 + tid) * 8;
    int row = idx >> 6, col = idx & 63;
    f16x8 v = *reinterpret_cast<const f16x8*>(vg + (size_t)row * 3072 + col);
    *reinterpret_cast<f16x8*>(sV + row * 72 + col) = v;
  }
#pragma unroll
  for (int p = 0; p < 2; ++p) {
    int idx = (p * 256 + tid) * 8;
    int row = idx >> 6, col = idx & 63;
    f16x8 v = *reinterpret_cast<const f16x8*>(zt + (size_t)bh * 4096 + idx);
    *reinterpret_cast<f16x8*>(sZ + row * 72 + col) = v;
  }
  __syncthreads();

  f32x4 acc[2][4] = {};
#pragma unroll
  for (int ks = 0; ks < 2; ++ks) {
    f16x8 av[2], bz[4];
#pragma unroll
    for (int m = 0; m < 2; ++m)
      av[m] = *reinterpret_cast<const f16x8*>(sV + (w * 32 + m * 16 + (l & 15)) * 72 + ks * 32 + ((l >> 4) << 3));
#pragma unroll
    for (int n = 0; n < 4; ++n)
      bz[n] = *reinterpret_cast<const f16x8*>(sZ + (n * 16 + (l & 15)) * 72 + ks * 32 + ((l >> 4) << 3));
#pragma unroll
    for (int m = 0; m < 2; ++m)
#pragma unroll
      for (int n = 0; n < 4; ++n)
        acc[m][n] = MFMA16(av[m], bz[n], acc[m][n]);
  }

#pragma unroll
  for (int m = 0; m < 2; ++m)
#pragma unroll
    for (int n = 0; n < 4; ++n)
#pragma unroll
      for (int j = 0; j < 4; ++j) {
        int s = st * 128 + w * 32 + m * 16 + ((l >> 4) << 2) + j;
        out2[(size_t)(b * 4096 + s) * 1024 + h * 64 + n * 16 + (l & 15)] = (f16)acc[m][n][j];
      }
}

// ---------------- launch ----------------
extern "C" void kernel_launch(void* const* d_in, const int* in_sizes, int n_in,
                              void* d_out, int out_size, void* d_ws, size_t ws_size,
                              hipStream_t stream) {
  const float* x  = (const float*)d_in[0];
  const float* Wq = (const float*)d_in[1];
  const float* Wk = (const float*)d_in[2];
  const float* Wv = (const float*)d_in[3];
  const float* Wo = (const float*)d_in[4];
  float* out = (float*)d_out;

  f16* xh    = (f16*)d_ws;               //  33,554,432  x (f16)
  f16* qkvh  = xh + 33554432;            // 100,663,296  [32768 x 3072] q|k|v
  f16* wqkvh = qkvh + 100663296;         //   3,145,728  [3072 x 1024]
  f16* woh   = wqkvh + 3145728;          //   1,048,576  [1024 x 1024]
  f16* zth   = woh + 1048576;            //     524,288  [128][64 zq][64 kd]
  f16* out2h = zth + 524288;             //  33,554,432  [32768 x 1024] merged

  cast_f32_to_f16<<<32768, 256, 0, stream>>>(x, xh, 33554432 / 4);
  cast_f32_to_f16<<<1024, 256, 0, stream>>>(Wq, wqkvh, 1048576 / 4);
  cast_f32_to_f16<<<1024, 256, 0, stream>>>(Wk, wqkvh + 1048576, 1048576 / 4);
  cast_f32_to_f16<<<1024, 256, 0, stream>>>(Wv, wqkvh + 2097152, 1048576 / 4);
  cast_f32_to_f16<<<1024, 256, 0, stream>>>(Wo, woh, 1048576 / 4);

  // QKV projection: [32768,3072] = xh * Wqkv^T   (1536 blocks, %8==0)
  gemm_bt_8ph<f16><<<128 * 12, 512, 0, stream>>>(xh, wqkvh, qkvh, 3072, 128);

  scores_softmax<<<128, 256, 0, stream>>>(qkvh, zth);
  pv_merge<<<dim3(32, 128), 256, 0, stream>>>(qkvh, zth, out2h);

  // output projection: d_out = out2 * Wo^T (f32 out)   (512 blocks, %8==0)
  gemm_bt_8ph<float><<<128 * 4, 512, 0, stream>>>(out2h, woh, out, 1024, 128);
}

// Round 6
// 425.714 us; speedup vs baseline: 1.8630x; 1.1551x over previous
//
#include <hip/hip_runtime.h>
#include <hip/hip_fp16.h>

typedef _Float16 f16;
typedef _Float16 f16x8 __attribute__((ext_vector_type(8)));
typedef _Float16 f16x4 __attribute__((ext_vector_type(4)));
typedef float    f32x4 __attribute__((ext_vector_type(4)));

#define MFMA16(a, b, c) __builtin_amdgcn_mfma_f32_16x16x32_f16((a), (b), (c), 0, 0, 0)

#define BARR() __builtin_amdgcn_s_barrier()
#define VMW4() asm volatile("s_waitcnt vmcnt(4)" ::: "memory")
#define VMW0() asm volatile("s_waitcnt vmcnt(0)" ::: "memory")
#define LGKM0() asm volatile("s_waitcnt lgkmcnt(0)" ::: "memory")
#define SB0()  __builtin_amdgcn_sched_barrier(0)

// global->LDS async, 16B/lane. Offset arg MUST be 0 (R4: imm applies to both
// global AND LDS address) — all offsets via pointer arithmetic.
#define GLOAD16(P, L)                                                          \
  __builtin_amdgcn_global_load_lds(                                            \
      (const __attribute__((address_space(1))) unsigned int*)(P),              \
      (__attribute__((address_space(3))) unsigned int*)(L), 16, 0, 0)

// ---------------- f32 -> f16 cast ----------------
__global__ __launch_bounds__(256) void cast_f32_to_f16(const float* __restrict__ src,
                                                       f16* __restrict__ dst, int n4) {
  int i = blockIdx.x * 256 + threadIdx.x;
  if (i >= n4) return;
  float4 v = reinterpret_cast<const float4*>(src)[i];
  f16x4 o = { (f16)v.x, (f16)v.y, (f16)v.z, (f16)v.w };
  reinterpret_cast<f16x4*>(dst)[i] = o;
}

// ============ 256x256 8-phase GEMM: C[M,N] = A[M,K] * B[N,K]^T, K=1024 ============
// 512 threads = 8 waves (2M x 4N), per-wave 128x64. BK=64, 2-buf 128 KiB LDS,
// st_16x32 swizzle. m201-faithful: RAW barriers (no memory-clobber wrapper!),
// per phase {reads; 1 half-tile stage; bar; lgkm0; SB0; setprio; 16 MFMA; setprio;
// bar}; counted vmcnt(4) ONLY at phases 4/8. Even tiles live in buf0, odd in buf1.
template <typename OutT>
__global__ __launch_bounds__(512, 1) void gemm_bt_8ph(const f16* __restrict__ A,
                                                      const f16* __restrict__ B,
                                                      OutT* __restrict__ C,
                                                      int N, int nby) {
  constexpr int K = 1024;
  __shared__ f16 lds[2][2][2][8192];   // [buf][A/B][half][16KB]

  const int tid = threadIdx.x;
  const int wid = tid >> 6, l = tid & 63;
  const int wr = wid >> 2, wc = wid & 3;

  // T1: bijective XCD swizzle (nwg % 8 == 0)
  const int nwg = gridDim.x;
  const int cpx = nwg >> 3;
  const int id = blockIdx.x;
  const int swz = (id & 7) * cpx + (id >> 3);
  const int by = swz % nby, bx = swz / nby;

  // staging source coords: physical LDS slot (j*512+tid)*16B -> logical (row,col)
  // via the inverse (== same, XOR involution) st_16x32 swizzle
  int r0s, c0s, r1s, c1s;
  {
    int rel = tid * 16;
    int sub = rel >> 10, q = rel & 1023;
    int inner = q ^ (((q >> 9) & 1) << 5);
    r0s = ((sub >> 1) << 4) + (inner >> 6);
    c0s = ((sub & 1) << 5) + ((inner & 63) >> 1);
    rel = (512 + tid) * 16;
    sub = rel >> 10; q = rel & 1023;
    inner = q ^ (((q >> 9) & 1) << 5);
    r1s = ((sub >> 1) << 4) + (inner >> 6);
    c1s = ((sub & 1) << 5) + ((inner & 63) >> 1);
  }
  // staging pointers sit at the iteration's base tile (2i); advance 128/iter
  const f16* gA0a = A + (size_t)(by * 256 + r0s) * K + c0s;
  const f16* gA0b = A + (size_t)(by * 256 + r1s) * K + c1s;
  const f16* gA1a = gA0a + 128 * K;
  const f16* gA1b = gA0b + 128 * K;
  const f16* gB0a = B + (size_t)(bx * 256 + r0s) * K + c0s;
  const f16* gB0b = B + (size_t)(bx * 256 + r1s) * K + c1s;
  const f16* gB1a = gB0a + 128 * K;
  const f16* gB1b = gB0b + 128 * K;

#define STAGE_P(G0, G1, EOFF, LB, MAT, H)                                      \
  { GLOAD16((G0) + (EOFF), &lds[LB][MAT][H][wid * 512]);                       \
    GLOAD16((G1) + (EOFF), &lds[LB][MAT][H][4096 + wid * 512]); }

  // hoisted lane-dependent swizzled read base (bytes within a [128][64] region)
  const int lane_rd = (((l & 15) << 6) + ((l >> 4) << 4)) ^ (((l >> 3) & 1) << 5);
  const char* rdA0 = (const char*)&lds[0][0][wr][0] + lane_rd;
  const char* rdA1 = (const char*)&lds[1][0][wr][0] + lane_rd;
  const char* rdB0 = (const char*)&lds[0][1][wc >> 1][0] + (wc & 1) * 8192 + lane_rd;
  const char* rdB1 = (const char*)&lds[1][1][wc >> 1][0] + (wc & 1) * 8192 + lane_rd;

  f16x8 af[4][2], bf0[2][2], bf1[2][2];
  f32x4 acc[8][4] = {};

#define READ_A_MH(RD, mh)                                                      \
  _Pragma("unroll") for (int mm = 0; mm < 4; ++mm)                             \
  _Pragma("unroll") for (int ks = 0; ks < 2; ++ks)                             \
    af[mm][ks] = *reinterpret_cast<const f16x8*>(                              \
        (RD) + (((((mh)*4 + mm) * 2) + ks) << 10));
#define READ_B_NH(DST, RD, nh)                                                 \
  _Pragma("unroll") for (int nn = 0; nn < 2; ++nn)                             \
  _Pragma("unroll") for (int ks = 0; ks < 2; ++ks)                             \
    DST[nn][ks] = *reinterpret_cast<const f16x8*>(                             \
        (RD) + (((((nh)*2 + nn) * 2) + ks) << 10));
#define CL2(BF, mh, nh)                                                        \
  __builtin_amdgcn_s_setprio(1);                                               \
  _Pragma("unroll") for (int mm = 0; mm < 4; ++mm)                             \
  _Pragma("unroll") for (int nn = 0; nn < 2; ++nn)                             \
  _Pragma("unroll") for (int ks = 0; ks < 2; ++ks)                             \
    acc[(mh)*4 + mm][(nh)*2 + nn] =                                            \
        MFMA16(af[mm][ks], BF[nn][ks], acc[(mh)*4 + mm][(nh)*2 + nn]);         \
  __builtin_amdgcn_s_setprio(0);

  // prologue: tile0 (buf0) fully + tile1 B-halves (buf1); gate leaves B(1) flying
  STAGE_P(gB0a, gB0b, 0, 0, 1, 0);
  STAGE_P(gB1a, gB1b, 0, 0, 1, 1);
  STAGE_P(gA0a, gA0b, 0, 0, 0, 0);
  STAGE_P(gA1a, gA1b, 0, 0, 0, 1);
  STAGE_P(gB0a, gB0b, 64, 1, 1, 0);
  STAGE_P(gB1a, gB1b, 64, 1, 1, 1);
  VMW4();
  BARR();

  for (int i = 0; i < 8; ++i) {
    const bool more = (i < 7);
    // p1: rd buf0{A.mh0, B.nh0}; stage A.h0(2i+1) -> buf1
    READ_A_MH(rdA0, 0); READ_B_NH(bf0, rdB0, 0);
    STAGE_P(gA0a, gA0b, 64, 1, 0, 0);
    BARR(); LGKM0(); SB0(); CL2(bf0, 0, 0); BARR();
    // p2: rd B.nh1; stage A.h1(2i+1) -> buf1
    READ_B_NH(bf1, rdB0, 1);
    STAGE_P(gA1a, gA1b, 64, 1, 0, 1);
    BARR(); LGKM0(); SB0(); CL2(bf1, 0, 1); BARR();
    // p3: rd A.mh1; stage B.h0(2i+2) -> buf0 (buf0.B reads drained here)
    READ_A_MH(rdA0, 1);
    if (more) STAGE_P(gB0a, gB0b, 128, 0, 1, 0);
    BARR(); LGKM0(); SB0(); CL2(bf1, 1, 1); BARR();
    // p4: stage B.h1(2i+2) -> buf0; gate: tile 2i+1 landed (leave p3/p4 stages)
    if (more) STAGE_P(gB1a, gB1b, 128, 0, 1, 1);
    BARR(); SB0(); CL2(bf0, 1, 0);
    if (more) { VMW4(); } else { VMW0(); }
    BARR();
    // p5: rd buf1{A.mh0, B.nh0}; stage A.h0(2i+2) -> buf0
    READ_A_MH(rdA1, 0); READ_B_NH(bf0, rdB1, 0);
    if (more) STAGE_P(gA0a, gA0b, 128, 0, 0, 0);
    BARR(); LGKM0(); SB0(); CL2(bf0, 0, 0); BARR();
    // p6: rd B.nh1; stage A.h1(2i+2) -> buf0
    READ_B_NH(bf1, rdB1, 1);
    if (more) STAGE_P(gA1a, gA1b, 128, 0, 0, 1);
    BARR(); LGKM0(); SB0(); CL2(bf1, 0, 1); BARR();
    // p7: rd A.mh1; stage B.h0(2i+3) -> buf1 (buf1.B reads drained here)
    READ_A_MH(rdA1, 1);
    if (more) STAGE_P(gB0a, gB0b, 192, 1, 1, 0);
    BARR(); LGKM0(); SB0(); CL2(bf1, 1, 1); BARR();
    // p8: stage B.h1(2i+3) -> buf1; gate: tile 2i+2 landed (leave p7/p8 stages)
    if (more) STAGE_P(gB1a, gB1b, 192, 1, 1, 1);
    BARR(); SB0(); CL2(bf0, 1, 0);
    if (more) VMW4();
    BARR();
    gA0a += 128; gA0b += 128; gA1a += 128; gA1b += 128;
    gB0a += 128; gB0b += 128; gB1a += 128; gB1b += 128;
  }

  const int rr = by * 256 + wr * 128 + ((l >> 4) << 2);
  const int cc = bx * 256 + wc * 64 + (l & 15);
#pragma unroll
  for (int m = 0; m < 8; ++m)
#pragma unroll
    for (int n = 0; n < 4; ++n)
#pragma unroll
      for (int j = 0; j < 4; ++j)
        C[(size_t)(rr + m * 16 + j) * N + cc + n * 16] = (OutT)acc[m][n][j];
#undef STAGE_P
#undef READ_A_MH
#undef READ_B_NH
#undef CL2
}

// ---------------- scores: partial K-reduction (16 segments of 256 y) ----------------
// part[bh][seg][kd][qd] (f32) = (1/8) * sum_{y in seg} K[y,kd] * Q[y,qd]
__global__ __launch_bounds__(256, 2) void scores_part(const f16* __restrict__ qkv,
                                                      float* __restrict__ part) {
  const int seg = blockIdx.x;            // 0..15
  const int bh = blockIdx.y;             // 0..127
  const int b = bh >> 4, h = bh & 15;
  const f16* qg = qkv + (size_t)b * 4096 * 3072 + h * 64;
  const f16* kg = qg + 1024;

  __shared__ f16 sQ[64 * 72];            // Qt[qd][y]
  __shared__ f16 sK[64 * 72];            // Kt[kd][y]

  const int tid = threadIdx.x;
  const int w = tid >> 6, l = tid & 63;

  f32x4 acc[4] = {};

  const int yb = seg * 256;
  for (int y0 = yb; y0 < yb + 256; y0 += 64) {
    __syncthreads();
#pragma unroll
    for (int cc = 0; cc < 2; ++cc) {
      const int c = 2 * w + cc;
      f16x8 vq = *reinterpret_cast<const f16x8*>(qg + (size_t)(y0 + l) * 3072 + c * 8);
      f16x8 vk = *reinterpret_cast<const f16x8*>(kg + (size_t)(y0 + l) * 3072 + c * 8);
#pragma unroll
      for (int j = 0; j < 8; ++j) {
        sQ[(c * 8 + j) * 72 + l] = vq[j];
        sK[(c * 8 + j) * 72 + l] = vk[j];
      }
    }
    __syncthreads();
#pragma unroll
    for (int ks = 0; ks < 2; ++ks) {
      f16x8 a = *reinterpret_cast<const f16x8*>(sK + (w * 16 + (l & 15)) * 72 + ks * 32 + ((l >> 4) << 3));
#pragma unroll
      for (int n = 0; n < 4; ++n) {
        f16x8 bq = *reinterpret_cast<const f16x8*>(sQ + (n * 16 + (l & 15)) * 72 + ks * 32 + ((l >> 4) << 3));
        acc[n] = MFMA16(a, bq, acc[n]);
      }
    }
  }

  float* dst = part + ((size_t)(bh * 16 + seg)) * 4096;
#pragma unroll
  for (int n = 0; n < 4; ++n)
#pragma unroll
    for (int j = 0; j < 4; ++j)
      dst[(w * 16 + ((l >> 4) << 2) + j) * 64 + n * 16 + (l & 15)] = acc[n][j] * 0.125f;
}

// ---------------- scores: combine partials + softmax -> Z^T ----------------
// One block per bh, one thread per kd row. zt[bh][zq*64 + kd] (f16).
__global__ __launch_bounds__(64) void scores_combine(const float* __restrict__ part,
                                                     f16* __restrict__ zt) {
  const int bh = blockIdx.x;
  const int kd = threadIdx.x;
  float s[64];
#pragma unroll
  for (int q = 0; q < 64; ++q) s[q] = 0.f;
  const float* p0 = part + (size_t)bh * 16 * 4096 + kd * 64;
  for (int seg = 0; seg < 16; ++seg) {
    const float4* ps = reinterpret_cast<const float4*>(p0 + seg * 4096);
#pragma unroll
    for (int q4 = 0; q4 < 16; ++q4) {
      float4 v = ps[q4];
      s[q4 * 4 + 0] += v.x; s[q4 * 4 + 1] += v.y;
      s[q4 * 4 + 2] += v.z; s[q4 * 4 + 3] += v.w;
    }
  }
  float mx = -1e30f;
#pragma unroll
  for (int q = 0; q < 64; ++q) mx = fmaxf(mx, s[q]);
  float sum = 0.f;
#pragma unroll
  for (int q = 0; q < 64; ++q) { float e = __expf(s[q] - mx); s[q] = e; sum += e; }
  float inv = 1.f / sum;
  f16* dst = zt + (size_t)bh * 4096 + kd;
#pragma unroll
  for (int q = 0; q < 64; ++q) dst[q * 64] = (f16)(s[q] * inv);
}

// ---------------- PV + head merge ----------------
__global__ __launch_bounds__(256, 2) void pv_merge(const f16* __restrict__ qkv,
                                                   const f16* __restrict__ zt,
                                                   f16* __restrict__ out2) {
  const int st = blockIdx.x;
  const int bh = blockIdx.y;
  const int b = bh >> 4, h = bh & 15;
  const f16* vg = qkv + (size_t)(b * 4096 + st * 128) * 3072 + 2048 + h * 64;

  __shared__ f16 sV[128 * 72];
  __shared__ f16 sZ[64 * 72];

  const int tid = threadIdx.x;
  const int w = tid >> 6, l = tid & 63;

#pragma unroll
  for (int p = 0; p < 4; ++p) {
    int idx = (p * 256 + tid) * 8;
    int row = idx >> 6, col = idx & 63;
    f16x8 v = *reinterpret_cast<const f16x8*>(vg + (size_t)row * 3072 + col);
    *reinterpret_cast<f16x8*>(sV + row * 72 + col) = v;
  }
#pragma unroll
  for (int p = 0; p < 2; ++p) {
    int idx = (p * 256 + tid) * 8;
    int row = idx >> 6, col = idx & 63;
    f16x8 v = *reinterpret_cast<const f16x8*>(zt + (size_t)bh * 4096 + idx);
    *reinterpret_cast<f16x8*>(sZ + row * 72 + col) = v;
  }
  __syncthreads();

  f32x4 acc[2][4] = {};
#pragma unroll
  for (int ks = 0; ks < 2; ++ks) {
    f16x8 av[2], bz[4];
#pragma unroll
    for (int m = 0; m < 2; ++m)
      av[m] = *reinterpret_cast<const f16x8*>(sV + (w * 32 + m * 16 + (l & 15)) * 72 + ks * 32 + ((l >> 4) << 3));
#pragma unroll
    for (int n = 0; n < 4; ++n)
      bz[n] = *reinterpret_cast<const f16x8*>(sZ + (n * 16 + (l & 15)) * 72 + ks * 32 + ((l >> 4) << 3));
#pragma unroll
    for (int m = 0; m < 2; ++m)
#pragma unroll
      for (int n = 0; n < 4; ++n)
        acc[m][n] = MFMA16(av[m], bz[n], acc[m][n]);
  }

#pragma unroll
  for (int m = 0; m < 2; ++m)
#pragma unroll
    for (int n = 0; n < 4; ++n)
#pragma unroll
      for (int j = 0; j < 4; ++j) {
        int s = st * 128 + w * 32 + m * 16 + ((l >> 4) << 2) + j;
        out2[(size_t)(b * 4096 + s) * 1024 + h * 64 + n * 16 + (l & 15)] = (f16)acc[m][n][j];
      }
}

// ---------------- launch ----------------
extern "C" void kernel_launch(void* const* d_in, const int* in_sizes, int n_in,
                              void* d_out, int out_size, void* d_ws, size_t ws_size,
                              hipStream_t stream) {
  const float* x  = (const float*)d_in[0];
  const float* Wq = (const float*)d_in[1];
  const float* Wk = (const float*)d_in[2];
  const float* Wv = (const float*)d_in[3];
  const float* Wo = (const float*)d_in[4];
  float* out = (float*)d_out;

  f16* xh    = (f16*)d_ws;               //  33,554,432  x (f16); dead after QKV GEMM
  f16* qkvh  = xh + 33554432;            // 100,663,296  [32768 x 3072] q|k|v
  f16* wqkvh = qkvh + 100663296;         //   3,145,728  [3072 x 1024]
  f16* woh   = wqkvh + 3145728;          //   1,048,576  [1024 x 1024]
  f16* zth   = woh + 1048576;            //     524,288  [128][64 zq][64 kd]
  f16* out2h = zth + 524288;             //  33,554,432  [32768 x 1024] merged
  float* part = (float*)d_ws;            // 33.5 MB partial scores — reuses dead xh

  cast_f32_to_f16<<<32768, 256, 0, stream>>>(x, xh, 33554432 / 4);
  cast_f32_to_f16<<<1024, 256, 0, stream>>>(Wq, wqkvh, 1048576 / 4);
  cast_f32_to_f16<<<1024, 256, 0, stream>>>(Wk, wqkvh + 1048576, 1048576 / 4);
  cast_f32_to_f16<<<1024, 256, 0, stream>>>(Wv, wqkvh + 2097152, 1048576 / 4);
  cast_f32_to_f16<<<1024, 256, 0, stream>>>(Wo, woh, 1048576 / 4);

  // QKV projection: [32768,3072] = xh * Wqkv^T   (1536 blocks, %8==0)
  gemm_bt_8ph<f16><<<128 * 12, 512, 0, stream>>>(xh, wqkvh, qkvh, 3072, 128);

  // scores: 16-way split K-reduction (2048 blocks), then combine + softmax
  scores_part<<<dim3(16, 128), 256, 0, stream>>>(qkvh, part);
  scores_combine<<<128, 64, 0, stream>>>(part, zth);

  pv_merge<<<dim3(32, 128), 256, 0, stream>>>(qkvh, zth, out2h);

  // output projection: d_out = out2 * Wo^T (f32 out)   (512 blocks, %8==0)
  gemm_bt_8ph<float><<<128 * 4, 512, 0, stream>>>(out2h, woh, out, 1024, 128);
}

// Round 7
// 415.620 us; speedup vs baseline: 1.9083x; 1.0243x over previous
//
#include <hip/hip_runtime.h>
#include <hip/hip_fp16.h>

typedef _Float16 f16;
typedef _Float16 f16x8 __attribute__((ext_vector_type(8)));
typedef _Float16 f16x4 __attribute__((ext_vector_type(4)));
typedef float    f32x4 __attribute__((ext_vector_type(4)));

#define MFMA16(a, b, c) __builtin_amdgcn_mfma_f32_16x16x32_f16((a), (b), (c), 0, 0, 0)

#define BARR() __builtin_amdgcn_s_barrier()
#define VMW6() asm volatile("s_waitcnt vmcnt(6)" ::: "memory")
#define VMW4() asm volatile("s_waitcnt vmcnt(4)" ::: "memory")
#define VMW0() asm volatile("s_waitcnt vmcnt(0)" ::: "memory")
#define LGKM0() asm volatile("s_waitcnt lgkmcnt(0)" ::: "memory")
#define SB0()  __builtin_amdgcn_sched_barrier(0)

// global->LDS async, 16B/lane. Offset arg MUST be 0 (R4: imm applies to both
// global AND LDS address) — all offsets via pointer arithmetic.
#define GLOAD16(P, L)                                                          \
  __builtin_amdgcn_global_load_lds(                                            \
      (const __attribute__((address_space(1))) unsigned int*)(P),              \
      (__attribute__((address_space(3))) unsigned int*)(L), 16, 0, 0)

// ---------------- f32 -> f16 cast ----------------
__global__ __launch_bounds__(256) void cast_f32_to_f16(const float* __restrict__ src,
                                                       f16* __restrict__ dst, int n4) {
  int i = blockIdx.x * 256 + threadIdx.x;
  if (i >= n4) return;
  float4 v = reinterpret_cast<const float4*>(src)[i];
  f16x4 o = { (f16)v.x, (f16)v.y, (f16)v.z, (f16)v.w };
  reinterpret_cast<f16x4*>(dst)[i] = o;
}

// ============ 256x256 8-phase GEMM: C[M,N] = A[M,K] * B[N,K]^T, K=1024 ============
// 512 threads = 8 waves (2M x 4N), per-wave 128x64. BK=64, 2-buf 128 KiB LDS,
// st_16x32 swizzle, raw barriers, counted vmcnt at p4/p8 only.
// A-staging shifted one phase early (A.h0 at prev-p8, A.h1 at p1) so the p4 gate
// drains loads issued >=3 phases earlier (HBM-latency headroom).
template <typename OutT>
__global__ __launch_bounds__(512, 1) void gemm_bt_8ph(const f16* __restrict__ A,
                                                      const f16* __restrict__ B,
                                                      OutT* __restrict__ C,
                                                      int N, int nby) {
  constexpr int K = 1024;
  __shared__ f16 lds[2][2][2][8192];   // [buf][A/B][half][16KB]

  const int tid = threadIdx.x;
  const int wid = tid >> 6, l = tid & 63;
  const int wr = wid >> 2, wc = wid & 3;

  // T1: bijective XCD swizzle (nwg % 8 == 0)
  const int nwg = gridDim.x;
  const int cpx = nwg >> 3;
  const int id = blockIdx.x;
  const int swz = (id & 7) * cpx + (id >> 3);
  const int by = swz % nby, bx = swz / nby;

  // staging source coords: physical LDS slot (j*512+tid)*16B -> logical (row,col)
  // via the inverse (== same, XOR involution) st_16x32 swizzle
  int r0s, c0s, r1s, c1s;
  {
    int rel = tid * 16;
    int sub = rel >> 10, q = rel & 1023;
    int inner = q ^ (((q >> 9) & 1) << 5);
    r0s = ((sub >> 1) << 4) + (inner >> 6);
    c0s = ((sub & 1) << 5) + ((inner & 63) >> 1);
    rel = (512 + tid) * 16;
    sub = rel >> 10; q = rel & 1023;
    inner = q ^ (((q >> 9) & 1) << 5);
    r1s = ((sub >> 1) << 4) + (inner >> 6);
    c1s = ((sub & 1) << 5) + ((inner & 63) >> 1);
  }
  // staging pointers sit at the iteration's base tile (2i); advance 128/iter
  const f16* gA0a = A + (size_t)(by * 256 + r0s) * K + c0s;
  const f16* gA0b = A + (size_t)(by * 256 + r1s) * K + c1s;
  const f16* gA1a = gA0a + 128 * K;
  const f16* gA1b = gA0b + 128 * K;
  const f16* gB0a = B + (size_t)(bx * 256 + r0s) * K + c0s;
  const f16* gB0b = B + (size_t)(bx * 256 + r1s) * K + c1s;
  const f16* gB1a = gB0a + 128 * K;
  const f16* gB1b = gB0b + 128 * K;

#define STAGE_P(G0, G1, EOFF, LB, MAT, H)                                      \
  { GLOAD16((G0) + (EOFF), &lds[LB][MAT][H][wid * 512]);                       \
    GLOAD16((G1) + (EOFF), &lds[LB][MAT][H][4096 + wid * 512]); }

  // hoisted lane-dependent swizzled read base (bytes within a [128][64] region)
  const int lane_rd = (((l & 15) << 6) + ((l >> 4) << 4)) ^ (((l >> 3) & 1) << 5);
  const char* rdA0 = (const char*)&lds[0][0][wr][0] + lane_rd;
  const char* rdA1 = (const char*)&lds[1][0][wr][0] + lane_rd;
  const char* rdB0 = (const char*)&lds[0][1][wc >> 1][0] + (wc & 1) * 8192 + lane_rd;
  const char* rdB1 = (const char*)&lds[1][1][wc >> 1][0] + (wc & 1) * 8192 + lane_rd;

  f16x8 af[4][2], bf0[2][2], bf1[2][2];
  f32x4 acc[8][4] = {};

#define READ_A_MH(RD, mh)                                                      \
  _Pragma("unroll") for (int mm = 0; mm < 4; ++mm)                             \
  _Pragma("unroll") for (int ks = 0; ks < 2; ++ks)                             \
    af[mm][ks] = *reinterpret_cast<const f16x8*>(                              \
        (RD) + (((((mh)*4 + mm) * 2) + ks) << 10));
#define READ_B_NH(DST, RD, nh)                                                 \
  _Pragma("unroll") for (int nn = 0; nn < 2; ++nn)                             \
  _Pragma("unroll") for (int ks = 0; ks < 2; ++ks)                             \
    DST[nn][ks] = *reinterpret_cast<const f16x8*>(                             \
        (RD) + (((((nh)*2 + nn) * 2) + ks) << 10));
#define CL2(BF, mh, nh)                                                        \
  __builtin_amdgcn_s_setprio(1);                                               \
  _Pragma("unroll") for (int mm = 0; mm < 4; ++mm)                             \
  _Pragma("unroll") for (int nn = 0; nn < 2; ++nn)                             \
  _Pragma("unroll") for (int ks = 0; ks < 2; ++ks)                             \
    acc[(mh)*4 + mm][(nh)*2 + nn] =                                            \
        MFMA16(af[mm][ks], BF[nn][ks], acc[(mh)*4 + mm][(nh)*2 + nn]);         \
  __builtin_amdgcn_s_setprio(0);

  // prologue: tile0 full (buf0) + tile1 {B.h0,B.h1,A.h0} (buf1); 14 loads
  STAGE_P(gB0a, gB0b, 0, 0, 1, 0);
  STAGE_P(gB1a, gB1b, 0, 0, 1, 1);
  STAGE_P(gA0a, gA0b, 0, 0, 0, 0);
  STAGE_P(gA1a, gA1b, 0, 0, 0, 1);
  STAGE_P(gB0a, gB0b, 64, 1, 1, 0);
  STAGE_P(gB1a, gB1b, 64, 1, 1, 1);
  STAGE_P(gA0a, gA0b, 64, 1, 0, 0);
  VMW6();            // tile0's 8 loads landed; tile1's 6 in flight
  BARR();

  for (int i = 0; i < 8; ++i) {
    const bool more = (i < 7);
    // p1: rd buf0{A.mh0, B.nh0}; stage A.h1(2i+1) -> buf1 (A.h0 staged prev p8)
    READ_A_MH(rdA0, 0); READ_B_NH(bf0, rdB0, 0);
    STAGE_P(gA1a, gA1b, 64, 1, 0, 1);
    BARR(); LGKM0(); SB0(); CL2(bf0, 0, 0); BARR();
    // p2: rd B.nh1  [no stage]
    READ_B_NH(bf1, rdB0, 1);
    BARR(); LGKM0(); SB0(); CL2(bf1, 0, 1); BARR();
    // p3: rd A.mh1; stage B.h0(2i+2) -> buf0 (buf0.B reads drained after p2)
    READ_A_MH(rdA0, 1);
    if (more) STAGE_P(gB0a, gB0b, 128, 0, 1, 0);
    BARR(); LGKM0(); SB0(); CL2(bf1, 1, 1); BARR();
    // p4: stage B.h1(2i+2) -> buf0; gate: tile 2i+1 landed
    //     outstanding 12 = {p7prev:2, p8prev:4, p1:2, p3:2, p4:2}; VMW4 drains
    //     p7prev..p1 (all of tile 2i+1), leaves p3/p4.
    if (more) STAGE_P(gB1a, gB1b, 128, 0, 1, 1);
    BARR(); SB0(); CL2(bf0, 1, 0);
    if (more) { VMW4(); } else { VMW0(); }
    BARR();
    // p5: rd buf1{A.mh0, B.nh0}; stage A.h0(2i+2) -> buf0 (buf0.A.h0 read p1)
    READ_A_MH(rdA1, 0); READ_B_NH(bf0, rdB1, 0);
    if (more) STAGE_P(gA0a, gA0b, 128, 0, 0, 0);
    BARR(); LGKM0(); SB0(); CL2(bf0, 0, 0); BARR();
    // p6: rd B.nh1; stage A.h1(2i+2) -> buf0 (buf0.A.h1 read p3)
    READ_B_NH(bf1, rdB1, 1);
    if (more) STAGE_P(gA1a, gA1b, 128, 0, 0, 1);
    BARR(); LGKM0(); SB0(); CL2(bf1, 0, 1); BARR();
    // p7: rd A.mh1; stage B.h0(2i+3) -> buf1 (buf1.B reads drained after p6)
    READ_A_MH(rdA1, 1);
    if (more) STAGE_P(gB0a, gB0b, 192, 1, 1, 0);
    BARR(); LGKM0(); SB0(); CL2(bf1, 1, 1); BARR();
    // p8: stage B.h1(2i+3) + A.h0(2i+3) -> buf1; gate: tile 2i+2 landed
    //     outstanding 14 = {p3:2,p4:2,p5:2,p6:2,p7:2,p8:4}; VMW6 drains p3..p6.
    if (more) { STAGE_P(gB1a, gB1b, 192, 1, 1, 1); STAGE_P(gA0a, gA0b, 192, 1, 0, 0); }
    BARR(); SB0(); CL2(bf0, 1, 0);
    if (more) VMW6();
    BARR();
    gA0a += 128; gA0b += 128; gA1a += 128; gA1b += 128;
    gB0a += 128; gB0b += 128; gB1a += 128; gB1b += 128;
  }

  const int rr = by * 256 + wr * 128 + ((l >> 4) << 2);
  const int cc = bx * 256 + wc * 64 + (l & 15);
#pragma unroll
  for (int m = 0; m < 8; ++m)
#pragma unroll
    for (int n = 0; n < 4; ++n)
#pragma unroll
      for (int j = 0; j < 4; ++j)
        C[(size_t)(rr + m * 16 + j) * N + cc + n * 16] = (OutT)acc[m][n][j];
#undef STAGE_P
#undef READ_A_MH
#undef READ_B_NH
#undef CL2
}

// ---------------- scores: partial K-reduction (16 segments of 256 y) ----------------
// part[bh][seg][kd][qd] (f32) = (1/8) * sum_{y in seg} K[y,kd] * Q[y,qd]
// Staging: each lane reads 64 CONTIGUOUS bytes (one full cache line) of its row:
// waves 0-1 -> Q, waves 2-3 -> K; lane g=(w&1)*64+l covers (row g>>1, col-half g&1).
__global__ __launch_bounds__(256, 2) void scores_part(const f16* __restrict__ qkv,
                                                      float* __restrict__ part) {
  const int seg = blockIdx.x;            // 0..15
  const int bh = blockIdx.y;             // 0..127
  const int b = bh >> 4, h = bh & 15;
  const f16* base = qkv + (size_t)b * 4096 * 3072 + h * 64;   // Q; K at +1024

  __shared__ f16 sQ[64 * 72];            // Qt[qd][y], pitch 72
  __shared__ f16 sK[64 * 72];            // Kt[kd][y]

  const int tid = threadIdx.x;
  const int w = tid >> 6, l = tid & 63;

  const int tsel = w >> 1;               // 0: Q, 1: K
  const int g = ((w & 1) << 6) + l;      // 0..127
  const int row = g >> 1;                // y-local 0..63
  const int ch = g & 1;                  // col-half (32 f16 = 64B)
  const f16* src = base + tsel * 1024 + (size_t)row * 3072 + ch * 32;
  f16* dstL = (tsel ? sK : sQ) + (ch * 32) * 72 + row;

  f32x4 acc[4] = {};

  const int yb = seg * 256;
  for (int y0 = yb; y0 < yb + 256; y0 += 64) {
    __syncthreads();
    const f16* s0 = src + (size_t)y0 * 3072;
    f16x8 v0 = *reinterpret_cast<const f16x8*>(s0);
    f16x8 v1 = *reinterpret_cast<const f16x8*>(s0 + 8);
    f16x8 v2 = *reinterpret_cast<const f16x8*>(s0 + 16);
    f16x8 v3 = *reinterpret_cast<const f16x8*>(s0 + 24);
#pragma unroll
    for (int j = 0; j < 8; ++j) {
      dstL[j * 72] = v0[j];
      dstL[(8 + j) * 72] = v1[j];
      dstL[(16 + j) * 72] = v2[j];
      dstL[(24 + j) * 72] = v3[j];
    }
    __syncthreads();
#pragma unroll
    for (int ks = 0; ks < 2; ++ks) {
      f16x8 a = *reinterpret_cast<const f16x8*>(sK + (w * 16 + (l & 15)) * 72 + ks * 32 + ((l >> 4) << 3));
#pragma unroll
      for (int n = 0; n < 4; ++n) {
        f16x8 bq = *reinterpret_cast<const f16x8*>(sQ + (n * 16 + (l & 15)) * 72 + ks * 32 + ((l >> 4) << 3));
        acc[n] = MFMA16(a, bq, acc[n]);
      }
    }
  }

  float* dst = part + ((size_t)(bh * 16 + seg)) * 4096;
#pragma unroll
  for (int n = 0; n < 4; ++n)
#pragma unroll
    for (int j = 0; j < 4; ++j)
      dst[(w * 16 + ((l >> 4) << 2) + j) * 64 + n * 16 + (l & 15)] = acc[n][j] * 0.125f;
}

// ---------------- scores: combine partials + softmax -> Z^T ----------------
__global__ __launch_bounds__(64) void scores_combine(const float* __restrict__ part,
                                                     f16* __restrict__ zt) {
  const int bh = blockIdx.x;
  const int kd = threadIdx.x;
  float s[64];
#pragma unroll
  for (int q = 0; q < 64; ++q) s[q] = 0.f;
  const float* p0 = part + (size_t)bh * 16 * 4096 + kd * 64;
  for (int seg = 0; seg < 16; ++seg) {
    const float4* ps = reinterpret_cast<const float4*>(p0 + seg * 4096);
#pragma unroll
    for (int q4 = 0; q4 < 16; ++q4) {
      float4 v = ps[q4];
      s[q4 * 4 + 0] += v.x; s[q4 * 4 + 1] += v.y;
      s[q4 * 4 + 2] += v.z; s[q4 * 4 + 3] += v.w;
    }
  }
  float mx = -1e30f;
#pragma unroll
  for (int q = 0; q < 64; ++q) mx = fmaxf(mx, s[q]);
  float sum = 0.f;
#pragma unroll
  for (int q = 0; q < 64; ++q) { float e = __expf(s[q] - mx); s[q] = e; sum += e; }
  float inv = 1.f / sum;
  f16* dst = zt + (size_t)bh * 4096 + kd;
#pragma unroll
  for (int q = 0; q < 64; ++q) dst[q * 64] = (f16)(s[q] * inv);
}

// ---------------- PV + head merge ----------------
__global__ __launch_bounds__(256, 2) void pv_merge(const f16* __restrict__ qkv,
                                                   const f16* __restrict__ zt,
                                                   f16* __restrict__ out2) {
  const int st = blockIdx.x;
  const int bh = blockIdx.y;
  const int b = bh >> 4, h = bh & 15;
  const f16* vg = qkv + (size_t)(b * 4096 + st * 128) * 3072 + 2048 + h * 64;

  __shared__ f16 sV[128 * 72];
  __shared__ f16 sZ[64 * 72];

  const int tid = threadIdx.x;
  const int w = tid >> 6, l = tid & 63;

#pragma unroll
  for (int p = 0; p < 4; ++p) {
    int idx = (p * 256 + tid) * 8;
    int row = idx >> 6, col = idx & 63;
    f16x8 v = *reinterpret_cast<const f16x8*>(vg + (size_t)row * 3072 + col);
    *reinterpret_cast<f16x8*>(sV + row * 72 + col) = v;
  }
#pragma unroll
  for (int p = 0; p < 2; ++p) {
    int idx = (p * 256 + tid) * 8;
    int row = idx >> 6, col = idx & 63;
    f16x8 v = *reinterpret_cast<const f16x8*>(zt + (size_t)bh * 4096 + idx);
    *reinterpret_cast<f16x8*>(sZ + row * 72 + col) = v;
  }
  __syncthreads();

  f32x4 acc[2][4] = {};
#pragma unroll
  for (int ks = 0; ks < 2; ++ks) {
    f16x8 av[2], bz[4];
#pragma unroll
    for (int m = 0; m < 2; ++m)
      av[m] = *reinterpret_cast<const f16x8*>(sV + (w * 32 + m * 16 + (l & 15)) * 72 + ks * 32 + ((l >> 4) << 3));
#pragma unroll
    for (int n = 0; n < 4; ++n)
      bz[n] = *reinterpret_cast<const f16x8*>(sZ + (n * 16 + (l & 15)) * 72 + ks * 32 + ((l >> 4) << 3));
#pragma unroll
    for (int m = 0; m < 2; ++m)
#pragma unroll
      for (int n = 0; n < 4; ++n)
        acc[m][n] = MFMA16(av[m], bz[n], acc[m][n]);
  }

#pragma unroll
  for (int m = 0; m < 2; ++m)
#pragma unroll
    for (int n = 0; n < 4; ++n)
#pragma unroll
      for (int j = 0; j < 4; ++j) {
        int s = st * 128 + w * 32 + m * 16 + ((l >> 4) << 2) + j;
        out2[(size_t)(b * 4096 + s) * 1024 + h * 64 + n * 16 + (l & 15)] = (f16)acc[m][n][j];
      }
}

// ---------------- launch ----------------
extern "C" void kernel_launch(void* const* d_in, const int* in_sizes, int n_in,
                              void* d_out, int out_size, void* d_ws, size_t ws_size,
                              hipStream_t stream) {
  const float* x  = (const float*)d_in[0];
  const float* Wq = (const float*)d_in[1];
  const float* Wk = (const float*)d_in[2];
  const float* Wv = (const float*)d_in[3];
  const float* Wo = (const float*)d_in[4];
  float* out = (float*)d_out;

  f16* xh    = (f16*)d_ws;               //  33,554,432  x (f16); dead after QKV GEMM
  f16* qkvh  = xh + 33554432;            // 100,663,296  [32768 x 3072] q|k|v
  f16* wqkvh = qkvh + 100663296;         //   3,145,728  [3072 x 1024]
  f16* woh   = wqkvh + 3145728;          //   1,048,576  [1024 x 1024]
  f16* zth   = woh + 1048576;            //     524,288  [128][64 zq][64 kd]
  f16* out2h = zth + 524288;             //  33,554,432  [32768 x 1024] merged
  float* part = (float*)d_ws;            // 33.5 MB partial scores — reuses dead xh

  cast_f32_to_f16<<<32768, 256, 0, stream>>>(x, xh, 33554432 / 4);
  cast_f32_to_f16<<<1024, 256, 0, stream>>>(Wq, wqkvh, 1048576 / 4);
  cast_f32_to_f16<<<1024, 256, 0, stream>>>(Wk, wqkvh + 1048576, 1048576 / 4);
  cast_f32_to_f16<<<1024, 256, 0, stream>>>(Wv, wqkvh + 2097152, 1048576 / 4);
  cast_f32_to_f16<<<1024, 256, 0, stream>>>(Wo, woh, 1048576 / 4);

  // QKV projection: [32768,3072] = xh * Wqkv^T   (1536 blocks, %8==0)
  gemm_bt_8ph<f16><<<128 * 12, 512, 0, stream>>>(xh, wqkvh, qkvh, 3072, 128);

  // scores: 16-way split K-reduction (2048 blocks), then combine + softmax
  scores_part<<<dim3(16, 128), 256, 0, stream>>>(qkvh, part);
  scores_combine<<<128, 64, 0, stream>>>(part, zth);

  pv_merge<<<dim3(32, 128), 256, 0, stream>>>(qkvh, zth, out2h);

  // output projection: d_out = out2 * Wo^T (f32 out)   (512 blocks, %8==0)
  gemm_bt_8ph<float><<<128 * 4, 512, 0, stream>>>(out2h, woh, out, 1024, 128);
}

// Round 8
// 414.837 us; speedup vs baseline: 1.9119x; 1.0019x over previous
//
#include <hip/hip_runtime.h>
#include <hip/hip_fp16.h>

typedef _Float16 f16;
typedef _Float16 f16x8 __attribute__((ext_vector_type(8)));
typedef _Float16 f16x4 __attribute__((ext_vector_type(4)));
typedef float    f32x4 __attribute__((ext_vector_type(4)));

#define MFMA16(a, b, c) __builtin_amdgcn_mfma_f32_16x16x32_f16((a), (b), (c), 0, 0, 0)

#define BARR() __builtin_amdgcn_s_barrier()
#define VMW6() asm volatile("s_waitcnt vmcnt(6)" ::: "memory")
#define VMW4() asm volatile("s_waitcnt vmcnt(4)" ::: "memory")
#define VMW0() asm volatile("s_waitcnt vmcnt(0)" ::: "memory")

// global->LDS async, 16B/lane. Offset arg MUST be 0 (R4: imm applies to both
// global AND LDS address) — all offsets via pointer arithmetic.
#define GLOAD16(P, L)                                                          \
  __builtin_amdgcn_global_load_lds(                                            \
      (const __attribute__((address_space(1))) unsigned int*)(P),              \
      (__attribute__((address_space(3))) unsigned int*)(L), 16, 0, 0)

// ---------------- f32 -> f16 cast ----------------
__global__ __launch_bounds__(256) void cast_f32_to_f16(const float* __restrict__ src,
                                                       f16* __restrict__ dst, int n4) {
  int i = blockIdx.x * 256 + threadIdx.x;
  if (i >= n4) return;
  float4 v = reinterpret_cast<const float4*>(src)[i];
  f16x4 o = { (f16)v.x, (f16)v.y, (f16)v.z, (f16)v.w };
  reinterpret_cast<f16x4*>(dst)[i] = o;
}

// ============ 256x256 8-phase GEMM: C[M,N] = A[M,K] * B[N,K]^T, K=1024 ============
// 512 threads = 8 waves (2M x 4N), per-wave 128x64. BK=64, 2-buf 128 KiB LDS,
// st_16x32 swizzle, raw barriers, counted vmcnt at p4/p8 only.
// NO explicit lgkmcnt drains: reads are C++ LDS loads, the compiler emits counted
// lgkmcnt between ds_read and MFMA (m97 evidence) — full LGKM0 drains defeated it.
template <typename OutT>
__global__ __launch_bounds__(512, 1) void gemm_bt_8ph(const f16* __restrict__ A,
                                                      const f16* __restrict__ B,
                                                      OutT* __restrict__ C,
                                                      int N, int nby) {
  constexpr int K = 1024;
  __shared__ f16 lds[2][2][2][8192];   // [buf][A/B][half][16KB]

  const int tid = threadIdx.x;
  const int wid = tid >> 6, l = tid & 63;
  const int wr = wid >> 2, wc = wid & 3;

  // T1: bijective XCD swizzle (nwg % 8 == 0)
  const int nwg = gridDim.x;
  const int cpx = nwg >> 3;
  const int id = blockIdx.x;
  const int swz = (id & 7) * cpx + (id >> 3);
  const int by = swz % nby, bx = swz / nby;

  // staging source coords: physical LDS slot (j*512+tid)*16B -> logical (row,col)
  // via the inverse (== same, XOR involution) st_16x32 swizzle
  int r0s, c0s, r1s, c1s;
  {
    int rel = tid * 16;
    int sub = rel >> 10, q = rel & 1023;
    int inner = q ^ (((q >> 9) & 1) << 5);
    r0s = ((sub >> 1) << 4) + (inner >> 6);
    c0s = ((sub & 1) << 5) + ((inner & 63) >> 1);
    rel = (512 + tid) * 16;
    sub = rel >> 10; q = rel & 1023;
    inner = q ^ (((q >> 9) & 1) << 5);
    r1s = ((sub >> 1) << 4) + (inner >> 6);
    c1s = ((sub & 1) << 5) + ((inner & 63) >> 1);
  }
  // staging pointers sit at the iteration's base tile (2i); advance 128/iter
  const f16* gA0a = A + (size_t)(by * 256 + r0s) * K + c0s;
  const f16* gA0b = A + (size_t)(by * 256 + r1s) * K + c1s;
  const f16* gA1a = gA0a + 128 * K;
  const f16* gA1b = gA0b + 128 * K;
  const f16* gB0a = B + (size_t)(bx * 256 + r0s) * K + c0s;
  const f16* gB0b = B + (size_t)(bx * 256 + r1s) * K + c1s;
  const f16* gB1a = gB0a + 128 * K;
  const f16* gB1b = gB0b + 128 * K;

#define STAGE_P(G0, G1, EOFF, LB, MAT, H)                                      \
  { GLOAD16((G0) + (EOFF), &lds[LB][MAT][H][wid * 512]);                       \
    GLOAD16((G1) + (EOFF), &lds[LB][MAT][H][4096 + wid * 512]); }

  // hoisted lane-dependent swizzled read base (bytes within a [128][64] region)
  const int lane_rd = (((l & 15) << 6) + ((l >> 4) << 4)) ^ (((l >> 3) & 1) << 5);
  const char* rdA0 = (const char*)&lds[0][0][wr][0] + lane_rd;
  const char* rdA1 = (const char*)&lds[1][0][wr][0] + lane_rd;
  const char* rdB0 = (const char*)&lds[0][1][wc >> 1][0] + (wc & 1) * 8192 + lane_rd;
  const char* rdB1 = (const char*)&lds[1][1][wc >> 1][0] + (wc & 1) * 8192 + lane_rd;

  f16x8 af[4][2], bf0[2][2], bf1[2][2];
  f32x4 acc[8][4] = {};

#define READ_A_MH(RD, mh)                                                      \
  _Pragma("unroll") for (int mm = 0; mm < 4; ++mm)                             \
  _Pragma("unroll") for (int ks = 0; ks < 2; ++ks)                             \
    af[mm][ks] = *reinterpret_cast<const f16x8*>(                              \
        (RD) + (((((mh)*4 + mm) * 2) + ks) << 10));
#define READ_B_NH(DST, RD, nh)                                                 \
  _Pragma("unroll") for (int nn = 0; nn < 2; ++nn)                             \
  _Pragma("unroll") for (int ks = 0; ks < 2; ++ks)                             \
    DST[nn][ks] = *reinterpret_cast<const f16x8*>(                             \
        (RD) + (((((nh)*2 + nn) * 2) + ks) << 10));
#define CL2(BF, mh, nh)                                                        \
  __builtin_amdgcn_s_setprio(1);                                               \
  _Pragma("unroll") for (int mm = 0; mm < 4; ++mm)                             \
  _Pragma("unroll") for (int nn = 0; nn < 2; ++nn)                             \
  _Pragma("unroll") for (int ks = 0; ks < 2; ++ks)                             \
    acc[(mh)*4 + mm][(nh)*2 + nn] =                                            \
        MFMA16(af[mm][ks], BF[nn][ks], acc[(mh)*4 + mm][(nh)*2 + nn]);         \
  __builtin_amdgcn_s_setprio(0);

  // prologue: tile0 full (buf0) + tile1 {B.h0,B.h1,A.h0} (buf1); 14 loads
  STAGE_P(gB0a, gB0b, 0, 0, 1, 0);
  STAGE_P(gB1a, gB1b, 0, 0, 1, 1);
  STAGE_P(gA0a, gA0b, 0, 0, 0, 0);
  STAGE_P(gA1a, gA1b, 0, 0, 0, 1);
  STAGE_P(gB0a, gB0b, 64, 1, 1, 0);
  STAGE_P(gB1a, gB1b, 64, 1, 1, 1);
  STAGE_P(gA0a, gA0b, 64, 1, 0, 0);
  VMW6();            // tile0's 8 loads landed; tile1's 6 in flight
  BARR();

  for (int i = 0; i < 8; ++i) {
    const bool more = (i < 7);
    // p1: rd buf0{A.mh0, B.nh0}; stage A.h1(2i+1) -> buf1 (A.h0 staged prev p8)
    READ_A_MH(rdA0, 0); READ_B_NH(bf0, rdB0, 0);
    STAGE_P(gA1a, gA1b, 64, 1, 0, 1);
    BARR(); CL2(bf0, 0, 0); BARR();
    // p2: rd B.nh1  [no stage]
    READ_B_NH(bf1, rdB0, 1);
    BARR(); CL2(bf1, 0, 1); BARR();
    // p3: rd A.mh1; stage B.h0(2i+2) -> buf0 (buf0.B reads consumed by p2)
    READ_A_MH(rdA0, 1);
    if (more) STAGE_P(gB0a, gB0b, 128, 0, 1, 0);
    BARR(); CL2(bf1, 1, 1); BARR();
    // p4: stage B.h1(2i+2) -> buf0; gate: tile 2i+1 landed
    //     outstanding 12 = {p7prev:2, p8prev:4, p1:2, p3:2, p4:2}; VMW4 drains
    //     p7prev..p1 (all of tile 2i+1), leaves p3/p4.
    if (more) STAGE_P(gB1a, gB1b, 128, 0, 1, 1);
    BARR(); CL2(bf0, 1, 0);
    if (more) { VMW4(); } else { VMW0(); }
    BARR();
    // p5: rd buf1{A.mh0, B.nh0}; stage A.h0(2i+2) -> buf0 (buf0.A.h0 read p1)
    READ_A_MH(rdA1, 0); READ_B_NH(bf0, rdB1, 0);
    if (more) STAGE_P(gA0a, gA0b, 128, 0, 0, 0);
    BARR(); CL2(bf0, 0, 0); BARR();
    // p6: rd B.nh1; stage A.h1(2i+2) -> buf0 (buf0.A.h1 read p3)
    READ_B_NH(bf1, rdB1, 1);
    if (more) STAGE_P(gA1a, gA1b, 128, 0, 0, 1);
    BARR(); CL2(bf1, 0, 1); BARR();
    // p7: rd A.mh1; stage B.h0(2i+3) -> buf1 (buf1.B reads consumed by p6)
    READ_A_MH(rdA1, 1);
    if (more) STAGE_P(gB0a, gB0b, 192, 1, 1, 0);
    BARR(); CL2(bf1, 1, 1); BARR();
    // p8: stage B.h1(2i+3) + A.h0(2i+3) -> buf1; gate: tile 2i+2 landed
    //     outstanding 14 = {p3:2,p4:2,p5:2,p6:2,p7:2,p8:4}; VMW6 drains p3..p6.
    if (more) { STAGE_P(gB1a, gB1b, 192, 1, 1, 1); STAGE_P(gA0a, gA0b, 192, 1, 0, 0); }
    BARR(); CL2(bf0, 1, 0);
    if (more) VMW6();
    BARR();
    gA0a += 128; gA0b += 128; gA1a += 128; gA1b += 128;
    gB0a += 128; gB0b += 128; gB1a += 128; gB1b += 128;
  }

  const int rr = by * 256 + wr * 128 + ((l >> 4) << 2);
  const int cc = bx * 256 + wc * 64 + (l & 15);
#pragma unroll
  for (int m = 0; m < 8; ++m)
#pragma unroll
    for (int n = 0; n < 4; ++n)
#pragma unroll
      for (int j = 0; j < 4; ++j)
        C[(size_t)(rr + m * 16 + j) * N + cc + n * 16] = (OutT)acc[m][n][j];
#undef STAGE_P
#undef READ_A_MH
#undef READ_B_NH
#undef CL2
}

// ---------------- scores: partial K-reduction (16 segments of 256 y) ----------------
// part[bh][seg][kd][qd] (f32) = (1/8) * sum_{y in seg} K[y,kd] * Q[y,qd]
// Staging: each lane reads 64 CONTIGUOUS bytes (one full cache line) of its row:
// waves 0-1 -> Q, waves 2-3 -> K; lane g=(w&1)*64+l covers (row g>>1, col-half g&1).
__global__ __launch_bounds__(256, 2) void scores_part(const f16* __restrict__ qkv,
                                                      float* __restrict__ part) {
  const int seg = blockIdx.x;            // 0..15
  const int bh = blockIdx.y;             // 0..127
  const int b = bh >> 4, h = bh & 15;
  const f16* base = qkv + (size_t)b * 4096 * 3072 + h * 64;   // Q; K at +1024

  __shared__ f16 sQ[64 * 72];            // Qt[qd][y], pitch 72
  __shared__ f16 sK[64 * 72];            // Kt[kd][y]

  const int tid = threadIdx.x;
  const int w = tid >> 6, l = tid & 63;

  const int tsel = w >> 1;               // 0: Q, 1: K
  const int g = ((w & 1) << 6) + l;      // 0..127
  const int row = g >> 1;                // y-local 0..63
  const int ch = g & 1;                  // col-half (32 f16 = 64B)
  const f16* src = base + tsel * 1024 + (size_t)row * 3072 + ch * 32;
  f16* dstL = (tsel ? sK : sQ) + (ch * 32) * 72 + row;

  f32x4 acc[4] = {};

  const int yb = seg * 256;
  for (int y0 = yb; y0 < yb + 256; y0 += 64) {
    __syncthreads();
    const f16* s0 = src + (size_t)y0 * 3072;
    f16x8 v0 = *reinterpret_cast<const f16x8*>(s0);
    f16x8 v1 = *reinterpret_cast<const f16x8*>(s0 + 8);
    f16x8 v2 = *reinterpret_cast<const f16x8*>(s0 + 16);
    f16x8 v3 = *reinterpret_cast<const f16x8*>(s0 + 24);
#pragma unroll
    for (int j = 0; j < 8; ++j) {
      dstL[j * 72] = v0[j];
      dstL[(8 + j) * 72] = v1[j];
      dstL[(16 + j) * 72] = v2[j];
      dstL[(24 + j) * 72] = v3[j];
    }
    __syncthreads();
#pragma unroll
    for (int ks = 0; ks < 2; ++ks) {
      f16x8 a = *reinterpret_cast<const f16x8*>(sK + (w * 16 + (l & 15)) * 72 + ks * 32 + ((l >> 4) << 3));
#pragma unroll
      for (int n = 0; n < 4; ++n) {
        f16x8 bq = *reinterpret_cast<const f16x8*>(sQ + (n * 16 + (l & 15)) * 72 + ks * 32 + ((l >> 4) << 3));
        acc[n] = MFMA16(a, bq, acc[n]);
      }
    }
  }

  float* dst = part + ((size_t)(bh * 16 + seg)) * 4096;
#pragma unroll
  for (int n = 0; n < 4; ++n)
#pragma unroll
    for (int j = 0; j < 4; ++j)
      dst[(w * 16 + ((l >> 4) << 2) + j) * 64 + n * 16 + (l & 15)] = acc[n][j] * 0.125f;
}

// ---------------- scores: combine partials + softmax -> Z^T ----------------
__global__ __launch_bounds__(64) void scores_combine(const float* __restrict__ part,
                                                     f16* __restrict__ zt) {
  const int bh = blockIdx.x;
  const int kd = threadIdx.x;
  float s[64];
#pragma unroll
  for (int q = 0; q < 64; ++q) s[q] = 0.f;
  const float* p0 = part + (size_t)bh * 16 * 4096 + kd * 64;
  for (int seg = 0; seg < 16; ++seg) {
    const float4* ps = reinterpret_cast<const float4*>(p0 + seg * 4096);
#pragma unroll
    for (int q4 = 0; q4 < 16; ++q4) {
      float4 v = ps[q4];
      s[q4 * 4 + 0] += v.x; s[q4 * 4 + 1] += v.y;
      s[q4 * 4 + 2] += v.z; s[q4 * 4 + 3] += v.w;
    }
  }
  float mx = -1e30f;
#pragma unroll
  for (int q = 0; q < 64; ++q) mx = fmaxf(mx, s[q]);
  float sum = 0.f;
#pragma unroll
  for (int q = 0; q < 64; ++q) { float e = __expf(s[q] - mx); s[q] = e; sum += e; }
  float inv = 1.f / sum;
  f16* dst = zt + (size_t)bh * 4096 + kd;
#pragma unroll
  for (int q = 0; q < 64; ++q) dst[q * 64] = (f16)(s[q] * inv);
}

// ---------------- PV + head merge ----------------
__global__ __launch_bounds__(256, 2) void pv_merge(const f16* __restrict__ qkv,
                                                   const f16* __restrict__ zt,
                                                   f16* __restrict__ out2) {
  const int st = blockIdx.x;
  const int bh = blockIdx.y;
  const int b = bh >> 4, h = bh & 15;
  const f16* vg = qkv + (size_t)(b * 4096 + st * 128) * 3072 + 2048 + h * 64;

  __shared__ f16 sV[128 * 72];
  __shared__ f16 sZ[64 * 72];

  const int tid = threadIdx.x;
  const int w = tid >> 6, l = tid & 63;

#pragma unroll
  for (int p = 0; p < 4; ++p) {
    int idx = (p * 256 + tid) * 8;
    int row = idx >> 6, col = idx & 63;
    f16x8 v = *reinterpret_cast<const f16x8*>(vg + (size_t)row * 3072 + col);
    *reinterpret_cast<f16x8*>(sV + row * 72 + col) = v;
  }
#pragma unroll
  for (int p = 0; p < 2; ++p) {
    int idx = (p * 256 + tid) * 8;
    int row = idx >> 6, col = idx & 63;
    f16x8 v = *reinterpret_cast<const f16x8*>(zt + (size_t)bh * 4096 + idx);
    *reinterpret_cast<f16x8*>(sZ + row * 72 + col) = v;
  }
  __syncthreads();

  f32x4 acc[2][4] = {};
#pragma unroll
  for (int ks = 0; ks < 2; ++ks) {
    f16x8 av[2], bz[4];
#pragma unroll
    for (int m = 0; m < 2; ++m)
      av[m] = *reinterpret_cast<const f16x8*>(sV + (w * 32 + m * 16 + (l & 15)) * 72 + ks * 32 + ((l >> 4) << 3));
#pragma unroll
    for (int n = 0; n < 4; ++n)
      bz[n] = *reinterpret_cast<const f16x8*>(sZ + (n * 16 + (l & 15)) * 72 + ks * 32 + ((l >> 4) << 3));
#pragma unroll
    for (int m = 0; m < 2; ++m)
#pragma unroll
      for (int n = 0; n < 4; ++n)
        acc[m][n] = MFMA16(av[m], bz[n], acc[m][n]);
  }

#pragma unroll
  for (int m = 0; m < 2; ++m)
#pragma unroll
    for (int n = 0; n < 4; ++n)
#pragma unroll
      for (int j = 0; j < 4; ++j) {
        int s = st * 128 + w * 32 + m * 16 + ((l >> 4) << 2) + j;
        out2[(size_t)(b * 4096 + s) * 1024 + h * 64 + n * 16 + (l & 15)] = (f16)acc[m][n][j];
      }
}

// ---------------- launch ----------------
extern "C" void kernel_launch(void* const* d_in, const int* in_sizes, int n_in,
                              void* d_out, int out_size, void* d_ws, size_t ws_size,
                              hipStream_t stream) {
  const float* x  = (const float*)d_in[0];
  const float* Wq = (const float*)d_in[1];
  const float* Wk = (const float*)d_in[2];
  const float* Wv = (const float*)d_in[3];
  const float* Wo = (const float*)d_in[4];
  float* out = (float*)d_out;

  f16* xh    = (f16*)d_ws;               //  33,554,432  x (f16); dead after QKV GEMM
  f16* qkvh  = xh + 33554432;            // 100,663,296  [32768 x 3072] q|k|v
  f16* wqkvh = qkvh + 100663296;         //   3,145,728  [3072 x 1024]
  f16* woh   = wqkvh + 3145728;          //   1,048,576  [1024 x 1024]
  f16* zth   = woh + 1048576;            //     524,288  [128][64 zq][64 kd]
  f16* out2h = zth + 524288;             //  33,554,432  [32768 x 1024] merged
  float* part = (float*)d_ws;            // 33.5 MB partial scores — reuses dead xh

  cast_f32_to_f16<<<32768, 256, 0, stream>>>(x, xh, 33554432 / 4);
  cast_f32_to_f16<<<1024, 256, 0, stream>>>(Wq, wqkvh, 1048576 / 4);
  cast_f32_to_f16<<<1024, 256, 0, stream>>>(Wk, wqkvh + 1048576, 1048576 / 4);
  cast_f32_to_f16<<<1024, 256, 0, stream>>>(Wv, wqkvh + 2097152, 1048576 / 4);
  cast_f32_to_f16<<<1024, 256, 0, stream>>>(Wo, woh, 1048576 / 4);

  // QKV projection: [32768,3072] = xh * Wqkv^T   (1536 blocks, %8==0)
  gemm_bt_8ph<f16><<<128 * 12, 512, 0, stream>>>(xh, wqkvh, qkvh, 3072, 128);

  // scores: 16-way split K-reduction (2048 blocks), then combine + softmax
  scores_part<<<dim3(16, 128), 256, 0, stream>>>(qkvh, part);
  scores_combine<<<128, 64, 0, stream>>>(part, zth);

  pv_merge<<<dim3(32, 128), 256, 0, stream>>>(qkvh, zth, out2h);

  // output projection: d_out = out2 * Wo^T (f32 out)   (512 blocks, %8==0)
  gemm_bt_8ph<float><<<128 * 4, 512, 0, stream>>>(out2h, woh, out, 1024, 128);
}

// Round 9
// 410.640 us; speedup vs baseline: 1.9314x; 1.0102x over previous
//
#include <hip/hip_runtime.h>
#include <hip/hip_fp16.h>

typedef _Float16 f16;
typedef _Float16 f16x8 __attribute__((ext_vector_type(8)));
typedef _Float16 f16x4 __attribute__((ext_vector_type(4)));
typedef float    f32x4 __attribute__((ext_vector_type(4)));

#define MFMA16(a, b, c) __builtin_amdgcn_mfma_f32_16x16x32_f16((a), (b), (c), 0, 0, 0)

#define BARR() __builtin_amdgcn_s_barrier()
#define VMW6() asm volatile("s_waitcnt vmcnt(6)" ::: "memory")
#define VMW4() asm volatile("s_waitcnt vmcnt(4)" ::: "memory")
#define VMW0() asm volatile("s_waitcnt vmcnt(0)" ::: "memory")

// global->LDS async, 16B/lane. Offset arg MUST be 0 (R4: imm applies to both
// global AND LDS address) — all offsets via pointer arithmetic.
#define GLOAD16(P, L)                                                          \
  __builtin_amdgcn_global_load_lds(                                            \
      (const __attribute__((address_space(1))) unsigned int*)(P),              \
      (__attribute__((address_space(3))) unsigned int*)(L), 16, 0, 0)

// ---------------- f32 -> f16 cast (x) ----------------
__global__ __launch_bounds__(256) void cast_f32_to_f16(const float* __restrict__ src,
                                                       f16* __restrict__ dst, int n4) {
  int i = blockIdx.x * 256 + threadIdx.x;
  if (i >= n4) return;
  float4 v = reinterpret_cast<const float4*>(src)[i];
  f16x4 o = { (f16)v.x, (f16)v.y, (f16)v.z, (f16)v.w };
  reinterpret_cast<f16x4*>(dst)[i] = o;
}

// ---------------- fused weight casts: Wq|Wk|Wv -> wqkvh, Wo -> woh ----------------
// 4096 blocks; blocks [k*1024,(k+1)*1024) handle tensor k (1M f32 each).
__global__ __launch_bounds__(256) void cast_weights(const float* __restrict__ Wq,
                                                    const float* __restrict__ Wk,
                                                    const float* __restrict__ Wv,
                                                    const float* __restrict__ Wo,
                                                    f16* __restrict__ wqkvh,
                                                    f16* __restrict__ woh) {
  const int k = blockIdx.x >> 10;
  const int i = (blockIdx.x & 1023) * 256 + threadIdx.x;   // < 262144 f32x4
  const float* src = (k == 0) ? Wq : (k == 1) ? Wk : (k == 2) ? Wv : Wo;
  f16* dst = (k == 3) ? woh : (wqkvh + k * 1048576);
  float4 v = reinterpret_cast<const float4*>(src)[i];
  f16x4 o = { (f16)v.x, (f16)v.y, (f16)v.z, (f16)v.w };
  reinterpret_cast<f16x4*>(dst)[i] = o;
}

// ============ 256x256 8-phase GEMM: C[M,N] = A[M,K] * B[N,K]^T, K=1024 ============
// 512 threads = 8 waves (2M x 4N), per-wave 128x64. BK=64, 2-buf 128 KiB LDS,
// st_16x32 swizzle, raw barriers, counted vmcnt at p4/p8 only.
// Block decode: bx FAST within each XCD chunk so the 12 consumers of each A-panel
// are co-resident on one XCD -> A read from HBM ~once (was 6x over-read, R8 FETCH).
template <typename OutT>
__global__ __launch_bounds__(512, 1) void gemm_bt_8ph(const f16* __restrict__ A,
                                                      const f16* __restrict__ B,
                                                      OutT* __restrict__ C,
                                                      int N, int nbx) {
  constexpr int K = 1024;
  __shared__ f16 lds[2][2][2][8192];   // [buf][A/B][half][16KB]

  const int tid = threadIdx.x;
  const int wid = tid >> 6, l = tid & 63;
  const int wr = wid >> 2, wc = wid & 3;

  // T1: bijective XCD swizzle (nwg % 8 == 0); bx fast within the XCD chunk
  const int nwg = gridDim.x;
  const int cpx = nwg >> 3;
  const int id = blockIdx.x;
  const int swz = (id & 7) * cpx + (id >> 3);
  const int bx = swz % nbx, by = swz / nbx;

  // staging source coords: physical LDS slot (j*512+tid)*16B -> logical (row,col)
  // via the inverse (== same, XOR involution) st_16x32 swizzle
  int r0s, c0s, r1s, c1s;
  {
    int rel = tid * 16;
    int sub = rel >> 10, q = rel & 1023;
    int inner = q ^ (((q >> 9) & 1) << 5);
    r0s = ((sub >> 1) << 4) + (inner >> 6);
    c0s = ((sub & 1) << 5) + ((inner & 63) >> 1);
    rel = (512 + tid) * 16;
    sub = rel >> 10; q = rel & 1023;
    inner = q ^ (((q >> 9) & 1) << 5);
    r1s = ((sub >> 1) << 4) + (inner >> 6);
    c1s = ((sub & 1) << 5) + ((inner & 63) >> 1);
  }
  // staging pointers sit at the iteration's base tile (2i); advance 128/iter
  const f16* gA0a = A + (size_t)(by * 256 + r0s) * K + c0s;
  const f16* gA0b = A + (size_t)(by * 256 + r1s) * K + c1s;
  const f16* gA1a = gA0a + 128 * K;
  const f16* gA1b = gA0b + 128 * K;
  const f16* gB0a = B + (size_t)(bx * 256 + r0s) * K + c0s;
  const f16* gB0b = B + (size_t)(bx * 256 + r1s) * K + c1s;
  const f16* gB1a = gB0a + 128 * K;
  const f16* gB1b = gB0b + 128 * K;

#define STAGE_P(G0, G1, EOFF, LB, MAT, H)                                      \
  { GLOAD16((G0) + (EOFF), &lds[LB][MAT][H][wid * 512]);                       \
    GLOAD16((G1) + (EOFF), &lds[LB][MAT][H][4096 + wid * 512]); }

  // hoisted lane-dependent swizzled read base (bytes within a [128][64] region)
  const int lane_rd = (((l & 15) << 6) + ((l >> 4) << 4)) ^ (((l >> 3) & 1) << 5);
  const char* rdA0 = (const char*)&lds[0][0][wr][0] + lane_rd;
  const char* rdA1 = (const char*)&lds[1][0][wr][0] + lane_rd;
  const char* rdB0 = (const char*)&lds[0][1][wc >> 1][0] + (wc & 1) * 8192 + lane_rd;
  const char* rdB1 = (const char*)&lds[1][1][wc >> 1][0] + (wc & 1) * 8192 + lane_rd;

  f16x8 af[4][2], bf0[2][2], bf1[2][2];
  f32x4 acc[8][4] = {};

#define READ_A_MH(RD, mh)                                                      \
  _Pragma("unroll") for (int mm = 0; mm < 4; ++mm)                             \
  _Pragma("unroll") for (int ks = 0; ks < 2; ++ks)                             \
    af[mm][ks] = *reinterpret_cast<const f16x8*>(                              \
        (RD) + (((((mh)*4 + mm) * 2) + ks) << 10));
#define READ_B_NH(DST, RD, nh)                                                 \
  _Pragma("unroll") for (int nn = 0; nn < 2; ++nn)                             \
  _Pragma("unroll") for (int ks = 0; ks < 2; ++ks)                             \
    DST[nn][ks] = *reinterpret_cast<const f16x8*>(                             \
        (RD) + (((((nh)*2 + nn) * 2) + ks) << 10));
#define CL2(BF, mh, nh)                                                        \
  __builtin_amdgcn_s_setprio(1);                                               \
  _Pragma("unroll") for (int mm = 0; mm < 4; ++mm)                             \
  _Pragma("unroll") for (int nn = 0; nn < 2; ++nn)                             \
  _Pragma("unroll") for (int ks = 0; ks < 2; ++ks)                             \
    acc[(mh)*4 + mm][(nh)*2 + nn] =                                            \
        MFMA16(af[mm][ks], BF[nn][ks], acc[(mh)*4 + mm][(nh)*2 + nn]);         \
  __builtin_amdgcn_s_setprio(0);

  // prologue: tile0 full (buf0) + tile1 {B.h0,B.h1,A.h0} (buf1); 14 loads
  STAGE_P(gB0a, gB0b, 0, 0, 1, 0);
  STAGE_P(gB1a, gB1b, 0, 0, 1, 1);
  STAGE_P(gA0a, gA0b, 0, 0, 0, 0);
  STAGE_P(gA1a, gA1b, 0, 0, 0, 1);
  STAGE_P(gB0a, gB0b, 64, 1, 1, 0);
  STAGE_P(gB1a, gB1b, 64, 1, 1, 1);
  STAGE_P(gA0a, gA0b, 64, 1, 0, 0);
  VMW6();            // tile0's 8 loads landed; tile1's 6 in flight
  BARR();

  for (int i = 0; i < 8; ++i) {
    const bool more = (i < 7);
    // p1: rd buf0{A.mh0, B.nh0}; stage A.h1(2i+1) -> buf1 (A.h0 staged prev p8)
    READ_A_MH(rdA0, 0); READ_B_NH(bf0, rdB0, 0);
    STAGE_P(gA1a, gA1b, 64, 1, 0, 1);
    BARR(); CL2(bf0, 0, 0); BARR();
    // p2: rd B.nh1  [no stage]
    READ_B_NH(bf1, rdB0, 1);
    BARR(); CL2(bf1, 0, 1); BARR();
    // p3: rd A.mh1; stage B.h0(2i+2) -> buf0 (buf0.B reads consumed by p2)
    READ_A_MH(rdA0, 1);
    if (more) STAGE_P(gB0a, gB0b, 128, 0, 1, 0);
    BARR(); CL2(bf1, 1, 1); BARR();
    // p4: stage B.h1(2i+2) -> buf0; gate: tile 2i+1 landed
    //     outstanding 12 = {p7prev:2, p8prev:4, p1:2, p3:2, p4:2}; VMW4 drains
    //     p7prev..p1 (all of tile 2i+1), leaves p3/p4.
    if (more) STAGE_P(gB1a, gB1b, 128, 0, 1, 1);
    BARR(); CL2(bf0, 1, 0);
    if (more) { VMW4(); } else { VMW0(); }
    BARR();
    // p5: rd buf1{A.mh0, B.nh0}; stage A.h0(2i+2) -> buf0 (buf0.A.h0 read p1)
    READ_A_MH(rdA1, 0); READ_B_NH(bf0, rdB1, 0);
    if (more) STAGE_P(gA0a, gA0b, 128, 0, 0, 0);
    BARR(); CL2(bf0, 0, 0); BARR();
    // p6: rd B.nh1; stage A.h1(2i+2) -> buf0 (buf0.A.h1 read p3)
    READ_B_NH(bf1, rdB1, 1);
    if (more) STAGE_P(gA1a, gA1b, 128, 0, 0, 1);
    BARR(); CL2(bf1, 0, 1); BARR();
    // p7: rd A.mh1; stage B.h0(2i+3) -> buf1 (buf1.B reads consumed by p6)
    READ_A_MH(rdA1, 1);
    if (more) STAGE_P(gB0a, gB0b, 192, 1, 1, 0);
    BARR(); CL2(bf1, 1, 1); BARR();
    // p8: stage B.h1(2i+3) + A.h0(2i+3) -> buf1; gate: tile 2i+2 landed
    //     outstanding 14 = {p3:2,p4:2,p5:2,p6:2,p7:2,p8:4}; VMW6 drains p3..p6.
    if (more) { STAGE_P(gB1a, gB1b, 192, 1, 1, 1); STAGE_P(gA0a, gA0b, 192, 1, 0, 0); }
    BARR(); CL2(bf0, 1, 0);
    if (more) VMW6();
    BARR();
    gA0a += 128; gA0b += 128; gA1a += 128; gA1b += 128;
    gB0a += 128; gB0b += 128; gB1a += 128; gB1b += 128;
  }

  const int rr = by * 256 + wr * 128 + ((l >> 4) << 2);
  const int cc = bx * 256 + wc * 64 + (l & 15);
#pragma unroll
  for (int m = 0; m < 8; ++m)
#pragma unroll
    for (int n = 0; n < 4; ++n)
#pragma unroll
      for (int j = 0; j < 4; ++j)
        C[(size_t)(rr + m * 16 + j) * N + cc + n * 16] = (OutT)acc[m][n][j];
#undef STAGE_P
#undef READ_A_MH
#undef READ_B_NH
#undef CL2
}

// ---------------- scores: partial K-reduction (16 segments of 256 y) ----------------
// part[bh][seg][kd][qd] (f32) = (1/8) * sum_{y in seg} K[y,kd] * Q[y,qd]
// Staging: each lane reads 64 CONTIGUOUS bytes (one full cache line) of its row:
// waves 0-1 -> Q, waves 2-3 -> K; lane g=(w&1)*64+l covers (row g>>1, col-half g&1).
__global__ __launch_bounds__(256, 2) void scores_part(const f16* __restrict__ qkv,
                                                      float* __restrict__ part) {
  const int seg = blockIdx.x;            // 0..15
  const int bh = blockIdx.y;             // 0..127
  const int b = bh >> 4, h = bh & 15;
  const f16* base = qkv + (size_t)b * 4096 * 3072 + h * 64;   // Q; K at +1024

  __shared__ f16 sQ[64 * 72];            // Qt[qd][y], pitch 72
  __shared__ f16 sK[64 * 72];            // Kt[kd][y]

  const int tid = threadIdx.x;
  const int w = tid >> 6, l = tid & 63;

  const int tsel = w >> 1;               // 0: Q, 1: K
  const int g = ((w & 1) << 6) + l;      // 0..127
  const int row = g >> 1;                // y-local 0..63
  const int ch = g & 1;                  // col-half (32 f16 = 64B)
  const f16* src = base + tsel * 1024 + (size_t)row * 3072 + ch * 32;
  f16* dstL = (tsel ? sK : sQ) + (ch * 32) * 72 + row;

  f32x4 acc[4] = {};

  const int yb = seg * 256;
  for (int y0 = yb; y0 < yb + 256; y0 += 64) {
    __syncthreads();
    const f16* s0 = src + (size_t)y0 * 3072;
    f16x8 v0 = *reinterpret_cast<const f16x8*>(s0);
    f16x8 v1 = *reinterpret_cast<const f16x8*>(s0 + 8);
    f16x8 v2 = *reinterpret_cast<const f16x8*>(s0 + 16);
    f16x8 v3 = *reinterpret_cast<const f16x8*>(s0 + 24);
#pragma unroll
    for (int j = 0; j < 8; ++j) {
      dstL[j * 72] = v0[j];
      dstL[(8 + j) * 72] = v1[j];
      dstL[(16 + j) * 72] = v2[j];
      dstL[(24 + j) * 72] = v3[j];
    }
    __syncthreads();
#pragma unroll
    for (int ks = 0; ks < 2; ++ks) {
      f16x8 a = *reinterpret_cast<const f16x8*>(sK + (w * 16 + (l & 15)) * 72 + ks * 32 + ((l >> 4) << 3));
#pragma unroll
      for (int n = 0; n < 4; ++n) {
        f16x8 bq = *reinterpret_cast<const f16x8*>(sQ + (n * 16 + (l & 15)) * 72 + ks * 32 + ((l >> 4) << 3));
        acc[n] = MFMA16(a, bq, acc[n]);
      }
    }
  }

  float* dst = part + ((size_t)(bh * 16 + seg)) * 4096;
#pragma unroll
  for (int n = 0; n < 4; ++n)
#pragma unroll
    for (int j = 0; j < 4; ++j)
      dst[(w * 16 + ((l >> 4) << 2) + j) * 64 + n * 16 + (l & 15)] = acc[n][j] * 0.125f;
}

// ---------------- scores: combine partials + softmax -> Z^T ----------------
__global__ __launch_bounds__(64) void scores_combine(const float* __restrict__ part,
                                                     f16* __restrict__ zt) {
  const int bh = blockIdx.x;
  const int kd = threadIdx.x;
  float s[64];
#pragma unroll
  for (int q = 0; q < 64; ++q) s[q] = 0.f;
  const float* p0 = part + (size_t)bh * 16 * 4096 + kd * 64;
  for (int seg = 0; seg < 16; ++seg) {
    const float4* ps = reinterpret_cast<const float4*>(p0 + seg * 4096);
#pragma unroll
    for (int q4 = 0; q4 < 16; ++q4) {
      float4 v = ps[q4];
      s[q4 * 4 + 0] += v.x; s[q4 * 4 + 1] += v.y;
      s[q4 * 4 + 2] += v.z; s[q4 * 4 + 3] += v.w;
    }
  }
  float mx = -1e30f;
#pragma unroll
  for (int q = 0; q < 64; ++q) mx = fmaxf(mx, s[q]);
  float sum = 0.f;
#pragma unroll
  for (int q = 0; q < 64; ++q) { float e = __expf(s[q] - mx); s[q] = e; sum += e; }
  float inv = 1.f / sum;
  f16* dst = zt + (size_t)bh * 4096 + kd;
#pragma unroll
  for (int q = 0; q < 64; ++q) dst[q * 64] = (f16)(s[q] * inv);
}

// ---------------- PV + head merge ----------------
__global__ __launch_bounds__(256, 2) void pv_merge(const f16* __restrict__ qkv,
                                                   const f16* __restrict__ zt,
                                                   f16* __restrict__ out2) {
  const int st = blockIdx.x;
  const int bh = blockIdx.y;
  const int b = bh >> 4, h = bh & 15;
  const f16* vg = qkv + (size_t)(b * 4096 + st * 128) * 3072 + 2048 + h * 64;

  __shared__ f16 sV[128 * 72];
  __shared__ f16 sZ[64 * 72];

  const int tid = threadIdx.x;
  const int w = tid >> 6, l = tid & 63;

#pragma unroll
  for (int p = 0; p < 4; ++p) {
    int idx = (p * 256 + tid) * 8;
    int row = idx >> 6, col = idx & 63;
    f16x8 v = *reinterpret_cast<const f16x8*>(vg + (size_t)row * 3072 + col);
    *reinterpret_cast<f16x8*>(sV + row * 72 + col) = v;
  }
#pragma unroll
  for (int p = 0; p < 2; ++p) {
    int idx = (p * 256 + tid) * 8;
    int row = idx >> 6, col = idx & 63;
    f16x8 v = *reinterpret_cast<const f16x8*>(zt + (size_t)bh * 4096 + idx);
    *reinterpret_cast<f16x8*>(sZ + row * 72 + col) = v;
  }
  __syncthreads();

  f32x4 acc[2][4] = {};
#pragma unroll
  for (int ks = 0; ks < 2; ++ks) {
    f16x8 av[2], bz[4];
#pragma unroll
    for (int m = 0; m < 2; ++m)
      av[m] = *reinterpret_cast<const f16x8*>(sV + (w * 32 + m * 16 + (l & 15)) * 72 + ks * 32 + ((l >> 4) << 3));
#pragma unroll
    for (int n = 0; n < 4; ++n)
      bz[n] = *reinterpret_cast<const f16x8*>(sZ + (n * 16 + (l & 15)) * 72 + ks * 32 + ((l >> 4) << 3));
#pragma unroll
    for (int m = 0; m < 2; ++m)
#pragma unroll
      for (int n = 0; n < 4; ++n)
        acc[m][n] = MFMA16(av[m], bz[n], acc[m][n]);
  }

#pragma unroll
  for (int m = 0; m < 2; ++m)
#pragma unroll
    for (int n = 0; n < 4; ++n)
#pragma unroll
      for (int j = 0; j < 4; ++j) {
        int s = st * 128 + w * 32 + m * 16 + ((l >> 4) << 2) + j;
        out2[(size_t)(b * 4096 + s) * 1024 + h * 64 + n * 16 + (l & 15)] = (f16)acc[m][n][j];
      }
}

// ---------------- launch ----------------
extern "C" void kernel_launch(void* const* d_in, const int* in_sizes, int n_in,
                              void* d_out, int out_size, void* d_ws, size_t ws_size,
                              hipStream_t stream) {
  const float* x  = (const float*)d_in[0];
  const float* Wq = (const float*)d_in[1];
  const float* Wk = (const float*)d_in[2];
  const float* Wv = (const float*)d_in[3];
  const float* Wo = (const float*)d_in[4];
  float* out = (float*)d_out;

  f16* xh    = (f16*)d_ws;               //  33,554,432  x (f16); dead after QKV GEMM
  f16* qkvh  = xh + 33554432;            // 100,663,296  [32768 x 3072] q|k|v
  f16* wqkvh = qkvh + 100663296;         //   3,145,728  [3072 x 1024]
  f16* woh   = wqkvh + 3145728;          //   1,048,576  [1024 x 1024]
  f16* zth   = woh + 1048576;            //     524,288  [128][64 zq][64 kd]
  f16* out2h = zth + 524288;             //  33,554,432  [32768 x 1024] merged
  float* part = (float*)d_ws;            // 33.5 MB partial scores — reuses dead xh

  cast_f32_to_f16<<<32768, 256, 0, stream>>>(x, xh, 33554432 / 4);
  cast_weights<<<4096, 256, 0, stream>>>(Wq, Wk, Wv, Wo, wqkvh, woh);

  // QKV projection: [32768,3072] = xh * Wqkv^T   (1536 blocks, %8==0, bx fast)
  gemm_bt_8ph<f16><<<128 * 12, 512, 0, stream>>>(xh, wqkvh, qkvh, 3072, 12);

  // scores: 16-way split K-reduction (2048 blocks), then combine + softmax
  scores_part<<<dim3(16, 128), 256, 0, stream>>>(qkvh, part);
  scores_combine<<<128, 64, 0, stream>>>(part, zth);

  pv_merge<<<dim3(32, 128), 256, 0, stream>>>(qkvh, zth, out2h);

  // output projection: d_out = out2 * Wo^T (f32 out)   (512 blocks, %8==0, bx fast)
  gemm_bt_8ph<float><<<128 * 4, 512, 0, stream>>>(out2h, woh, out, 1024, 4);
}

// Round 10
// 384.691 us; speedup vs baseline: 2.0617x; 1.0675x over previous
//
#include <hip/hip_runtime.h>
#include <hip/hip_fp16.h>

typedef _Float16 f16;
typedef _Float16 f16x8 __attribute__((ext_vector_type(8)));
typedef _Float16 f16x4 __attribute__((ext_vector_type(4)));
typedef float    f32x4 __attribute__((ext_vector_type(4)));

#define MFMA16(a, b, c) __builtin_amdgcn_mfma_f32_16x16x32_f16((a), (b), (c), 0, 0, 0)

#define BARR() __builtin_amdgcn_s_barrier()
#define VMW6() asm volatile("s_waitcnt vmcnt(6)" ::: "memory")
#define VMW4() asm volatile("s_waitcnt vmcnt(4)" ::: "memory")
#define VMW0() asm volatile("s_waitcnt vmcnt(0)" ::: "memory")

// global->LDS async, 16B/lane. Offset arg MUST be 0 (R4: imm applies to both
// global AND LDS address) — all offsets via pointer arithmetic.
#define GLOAD16(P, L)                                                          \
  __builtin_amdgcn_global_load_lds(                                            \
      (const __attribute__((address_space(1))) unsigned int*)(P),              \
      (__attribute__((address_space(3))) unsigned int*)(L), 16, 0, 0)

// ---------------- f32 -> f16 cast (x) ----------------
__global__ __launch_bounds__(256) void cast_f32_to_f16(const float* __restrict__ src,
                                                       f16* __restrict__ dst, int n4) {
  int i = blockIdx.x * 256 + threadIdx.x;
  if (i >= n4) return;
  float4 v = reinterpret_cast<const float4*>(src)[i];
  f16x4 o = { (f16)v.x, (f16)v.y, (f16)v.z, (f16)v.w };
  reinterpret_cast<f16x4*>(dst)[i] = o;
}

// ---------------- fused weight casts: Wq|Wk|Wv -> wqkvh, Wo -> woh ----------------
__global__ __launch_bounds__(256) void cast_weights(const float* __restrict__ Wq,
                                                    const float* __restrict__ Wk,
                                                    const float* __restrict__ Wv,
                                                    const float* __restrict__ Wo,
                                                    f16* __restrict__ wqkvh,
                                                    f16* __restrict__ woh) {
  const int k = blockIdx.x >> 10;
  const int i = (blockIdx.x & 1023) * 256 + threadIdx.x;   // < 262144 f32x4
  const float* src = (k == 0) ? Wq : (k == 1) ? Wk : (k == 2) ? Wv : Wo;
  f16* dst = (k == 3) ? woh : (wqkvh + k * 1048576);
  float4 v = reinterpret_cast<const float4*>(src)[i];
  f16x4 o = { (f16)v.x, (f16)v.y, (f16)v.z, (f16)v.w };
  reinterpret_cast<f16x4*>(dst)[i] = o;
}

// ============ 256x256 8-phase GEMM: C[M,N] = A[M,K] * B[N,K]^T, K=1024 ============
// 512 threads = 8 waves (2M x 4N), per-wave 128x64. BK=64, 2-buf 128 KiB LDS,
// st_16x32 swizzle, raw barriers, counted vmcnt at p4/p8 only, bx-fast XCD swizzle.
template <typename OutT>
__global__ __launch_bounds__(512, 1) void gemm_bt_8ph(const f16* __restrict__ A,
                                                      const f16* __restrict__ B,
                                                      OutT* __restrict__ C,
                                                      int N, int nbx) {
  constexpr int K = 1024;
  __shared__ f16 lds[2][2][2][8192];   // [buf][A/B][half][16KB]

  const int tid = threadIdx.x;
  const int wid = tid >> 6, l = tid & 63;
  const int wr = wid >> 2, wc = wid & 3;

  // T1: bijective XCD swizzle (nwg % 8 == 0); bx fast within the XCD chunk
  const int nwg = gridDim.x;
  const int cpx = nwg >> 3;
  const int id = blockIdx.x;
  const int swz = (id & 7) * cpx + (id >> 3);
  const int bx = swz % nbx, by = swz / nbx;

  // staging source coords: physical LDS slot (j*512+tid)*16B -> logical (row,col)
  // via the inverse (== same, XOR involution) st_16x32 swizzle
  int r0s, c0s, r1s, c1s;
  {
    int rel = tid * 16;
    int sub = rel >> 10, q = rel & 1023;
    int inner = q ^ (((q >> 9) & 1) << 5);
    r0s = ((sub >> 1) << 4) + (inner >> 6);
    c0s = ((sub & 1) << 5) + ((inner & 63) >> 1);
    rel = (512 + tid) * 16;
    sub = rel >> 10; q = rel & 1023;
    inner = q ^ (((q >> 9) & 1) << 5);
    r1s = ((sub >> 1) << 4) + (inner >> 6);
    c1s = ((sub & 1) << 5) + ((inner & 63) >> 1);
  }
  // staging pointers sit at the iteration's base tile (2i); advance 128/iter
  const f16* gA0a = A + (size_t)(by * 256 + r0s) * K + c0s;
  const f16* gA0b = A + (size_t)(by * 256 + r1s) * K + c1s;
  const f16* gA1a = gA0a + 128 * K;
  const f16* gA1b = gA0b + 128 * K;
  const f16* gB0a = B + (size_t)(bx * 256 + r0s) * K + c0s;
  const f16* gB0b = B + (size_t)(bx * 256 + r1s) * K + c1s;
  const f16* gB1a = gB0a + 128 * K;
  const f16* gB1b = gB0b + 128 * K;

#define STAGE_P(G0, G1, EOFF, LB, MAT, H)                                      \
  { GLOAD16((G0) + (EOFF), &lds[LB][MAT][H][wid * 512]);                       \
    GLOAD16((G1) + (EOFF), &lds[LB][MAT][H][4096 + wid * 512]); }

  // hoisted lane-dependent swizzled read base (bytes within a [128][64] region)
  const int lane_rd = (((l & 15) << 6) + ((l >> 4) << 4)) ^ (((l >> 3) & 1) << 5);
  const char* rdA0 = (const char*)&lds[0][0][wr][0] + lane_rd;
  const char* rdA1 = (const char*)&lds[1][0][wr][0] + lane_rd;
  const char* rdB0 = (const char*)&lds[0][1][wc >> 1][0] + (wc & 1) * 8192 + lane_rd;
  const char* rdB1 = (const char*)&lds[1][1][wc >> 1][0] + (wc & 1) * 8192 + lane_rd;

  f16x8 af[4][2], bf0[2][2], bf1[2][2];
  f32x4 acc[8][4] = {};

#define READ_A_MH(RD, mh)                                                      \
  _Pragma("unroll") for (int mm = 0; mm < 4; ++mm)                             \
  _Pragma("unroll") for (int ks = 0; ks < 2; ++ks)                             \
    af[mm][ks] = *reinterpret_cast<const f16x8*>(                              \
        (RD) + (((((mh)*4 + mm) * 2) + ks) << 10));
#define READ_B_NH(DST, RD, nh)                                                 \
  _Pragma("unroll") for (int nn = 0; nn < 2; ++nn)                             \
  _Pragma("unroll") for (int ks = 0; ks < 2; ++ks)                             \
    DST[nn][ks] = *reinterpret_cast<const f16x8*>(                             \
        (RD) + (((((nh)*2 + nn) * 2) + ks) << 10));
#define CL2(BF, mh, nh)                                                        \
  __builtin_amdgcn_s_setprio(1);                                               \
  _Pragma("unroll") for (int mm = 0; mm < 4; ++mm)                             \
  _Pragma("unroll") for (int nn = 0; nn < 2; ++nn)                             \
  _Pragma("unroll") for (int ks = 0; ks < 2; ++ks)                             \
    acc[(mh)*4 + mm][(nh)*2 + nn] =                                            \
        MFMA16(af[mm][ks], BF[nn][ks], acc[(mh)*4 + mm][(nh)*2 + nn]);         \
  __builtin_amdgcn_s_setprio(0);

  // prologue: tile0 full (buf0) + tile1 {B.h0,B.h1,A.h0} (buf1); 14 loads
  STAGE_P(gB0a, gB0b, 0, 0, 1, 0);
  STAGE_P(gB1a, gB1b, 0, 0, 1, 1);
  STAGE_P(gA0a, gA0b, 0, 0, 0, 0);
  STAGE_P(gA1a, gA1b, 0, 0, 0, 1);
  STAGE_P(gB0a, gB0b, 64, 1, 1, 0);
  STAGE_P(gB1a, gB1b, 64, 1, 1, 1);
  STAGE_P(gA0a, gA0b, 64, 1, 0, 0);
  VMW6();            // tile0's 8 loads landed; tile1's 6 in flight
  BARR();

  for (int i = 0; i < 8; ++i) {
    const bool more = (i < 7);
    // p1: rd buf0{A.mh0, B.nh0}; stage A.h1(2i+1) -> buf1 (A.h0 staged prev p8)
    READ_A_MH(rdA0, 0); READ_B_NH(bf0, rdB0, 0);
    STAGE_P(gA1a, gA1b, 64, 1, 0, 1);
    BARR(); CL2(bf0, 0, 0); BARR();
    // p2: rd B.nh1  [no stage]
    READ_B_NH(bf1, rdB0, 1);
    BARR(); CL2(bf1, 0, 1); BARR();
    // p3: rd A.mh1; stage B.h0(2i+2) -> buf0 (buf0.B reads consumed by p2)
    READ_A_MH(rdA0, 1);
    if (more) STAGE_P(gB0a, gB0b, 128, 0, 1, 0);
    BARR(); CL2(bf1, 1, 1); BARR();
    // p4: stage B.h1(2i+2) -> buf0; gate: tile 2i+1 landed
    if (more) STAGE_P(gB1a, gB1b, 128, 0, 1, 1);
    BARR(); CL2(bf0, 1, 0);
    if (more) { VMW4(); } else { VMW0(); }
    BARR();
    // p5: rd buf1{A.mh0, B.nh0}; stage A.h0(2i+2) -> buf0 (buf0.A.h0 read p1)
    READ_A_MH(rdA1, 0); READ_B_NH(bf0, rdB1, 0);
    if (more) STAGE_P(gA0a, gA0b, 128, 0, 0, 0);
    BARR(); CL2(bf0, 0, 0); BARR();
    // p6: rd B.nh1; stage A.h1(2i+2) -> buf0 (buf0.A.h1 read p3)
    READ_B_NH(bf1, rdB1, 1);
    if (more) STAGE_P(gA1a, gA1b, 128, 0, 0, 1);
    BARR(); CL2(bf1, 0, 1); BARR();
    // p7: rd A.mh1; stage B.h0(2i+3) -> buf1 (buf1.B reads consumed by p6)
    READ_A_MH(rdA1, 1);
    if (more) STAGE_P(gB0a, gB0b, 192, 1, 1, 0);
    BARR(); CL2(bf1, 1, 1); BARR();
    // p8: stage B.h1(2i+3) + A.h0(2i+3) -> buf1; gate: tile 2i+2 landed
    if (more) { STAGE_P(gB1a, gB1b, 192, 1, 1, 1); STAGE_P(gA0a, gA0b, 192, 1, 0, 0); }
    BARR(); CL2(bf0, 1, 0);
    if (more) VMW6();
    BARR();
    gA0a += 128; gA0b += 128; gA1a += 128; gA1b += 128;
    gB0a += 128; gB0b += 128; gB1a += 128; gB1b += 128;
  }

  const int rr = by * 256 + wr * 128 + ((l >> 4) << 2);
  const int cc = bx * 256 + wc * 64 + (l & 15);
#pragma unroll
  for (int m = 0; m < 8; ++m)
#pragma unroll
    for (int n = 0; n < 4; ++n)
#pragma unroll
      for (int j = 0; j < 4; ++j)
        C[(size_t)(rr + m * 16 + j) * N + cc + n * 16] = (OutT)acc[m][n][j];
#undef STAGE_P
#undef READ_A_MH
#undef READ_B_NH
#undef CL2
}

// ---------------- scores: partial K-reduction (16 segments of 256 y) ----------------
// part[bh][seg][kd][qd] (f16) = (1/8) * sum_{y in seg} K[y,kd] * Q[y,qd]
// Single 256-y stage: sQ/sK [64 d][264 pitch] (67.6 KB LDS, 2 blocks/CU), ONE barrier.
// Each lane loads 64 contiguous bytes per rep (full cache line); transpose-store
// is 2-lanes/bank (free). MFMA over 8 y-windows of 32.
__global__ __launch_bounds__(256, 2) void scores_part(const f16* __restrict__ qkv,
                                                      f16* __restrict__ part) {
  const int seg = blockIdx.x;            // 0..15
  const int bh = blockIdx.y;             // 0..127
  const int b = bh >> 4, h = bh & 15;
  const f16* base = qkv + (size_t)b * 4096 * 3072 + h * 64;   // Q; K at +1024

  __shared__ f16 sQ[64 * 264];           // Qt[qd][y], pitch 264
  __shared__ f16 sK[64 * 264];           // Kt[kd][y]

  const int tid = threadIdx.x;
  const int w = tid >> 6, l = tid & 63;

  const int tsel = w >> 1;               // 0: Q, 1: K
  const int g = ((w & 1) << 6) + l;      // 0..127
  const int r0 = g >> 1;                 // y-local 0..63 (+64*rep)
  const int ch = g & 1;                  // col-half (32 f16 = 64B)
  const f16* src = base + tsel * 1024 + (size_t)(seg * 256 + r0) * 3072 + ch * 32;
  f16* dstL = (tsel ? sK : sQ) + (ch * 32) * 264 + r0;

#pragma unroll
  for (int rep = 0; rep < 4; ++rep) {
    const f16* s0 = src + (size_t)(rep * 64) * 3072;
    f16x8 v0 = *reinterpret_cast<const f16x8*>(s0);
    f16x8 v1 = *reinterpret_cast<const f16x8*>(s0 + 8);
    f16x8 v2 = *reinterpret_cast<const f16x8*>(s0 + 16);
    f16x8 v3 = *reinterpret_cast<const f16x8*>(s0 + 24);
    f16* d = dstL + rep * 64;
#pragma unroll
    for (int j = 0; j < 8; ++j) {
      d[j * 264] = v0[j];
      d[(8 + j) * 264] = v1[j];
      d[(16 + j) * 264] = v2[j];
      d[(24 + j) * 264] = v3[j];
    }
  }
  __syncthreads();

  f32x4 acc[4] = {};
#pragma unroll
  for (int ys = 0; ys < 8; ++ys) {
    f16x8 a = *reinterpret_cast<const f16x8*>(sK + (w * 16 + (l & 15)) * 264 + ys * 32 + ((l >> 4) << 3));
#pragma unroll
    for (int n = 0; n < 4; ++n) {
      f16x8 bq = *reinterpret_cast<const f16x8*>(sQ + (n * 16 + (l & 15)) * 264 + ys * 32 + ((l >> 4) << 3));
      acc[n] = MFMA16(a, bq, acc[n]);
    }
  }

  f16* dst = part + ((size_t)(bh * 16 + seg)) * 4096;
#pragma unroll
  for (int n = 0; n < 4; ++n)
#pragma unroll
    for (int j = 0; j < 4; ++j)
      dst[(w * 16 + ((l >> 4) << 2) + j) * 64 + n * 16 + (l & 15)] = (f16)(acc[n][j] * 0.125f);
}

// ---------------- scores: combine partials + softmax -> Z^T ----------------
// 256 threads/block: thread (kd = tid>>2, qg = tid&3) owns 16 qd of one kd row;
// softmax reduced across the 4-lane group via shfl_xor. zt[bh][zq*64+kd] (f16).
__global__ __launch_bounds__(256) void scores_combine(const f16* __restrict__ part,
                                                      f16* __restrict__ zt) {
  const int bh = blockIdx.x;
  const int kd = threadIdx.x >> 2;
  const int qg = threadIdx.x & 3;
  const f16* p0 = part + (size_t)bh * 16 * 4096 + kd * 64 + qg * 16;
  float s[16];
#pragma unroll
  for (int j = 0; j < 16; ++j) s[j] = 0.f;
#pragma unroll 4
  for (int seg = 0; seg < 16; ++seg) {
    f16x8 a = *reinterpret_cast<const f16x8*>(p0 + seg * 4096);
    f16x8 c = *reinterpret_cast<const f16x8*>(p0 + seg * 4096 + 8);
#pragma unroll
    for (int j = 0; j < 8; ++j) { s[j] += (float)a[j]; s[8 + j] += (float)c[j]; }
  }
  float mx = s[0];
#pragma unroll
  for (int j = 1; j < 16; ++j) mx = fmaxf(mx, s[j]);
  mx = fmaxf(mx, __shfl_xor(mx, 1));
  mx = fmaxf(mx, __shfl_xor(mx, 2));
  float sum = 0.f;
#pragma unroll
  for (int j = 0; j < 16; ++j) { float e = __expf(s[j] - mx); s[j] = e; sum += e; }
  sum += __shfl_xor(sum, 1);
  sum += __shfl_xor(sum, 2);
  float inv = 1.f / sum;
  f16* dst = zt + (size_t)bh * 4096 + (qg * 16) * 64 + kd;   // zt[q*64 + kd]
#pragma unroll
  for (int j = 0; j < 16; ++j) dst[j * 64] = (f16)(s[j] * inv);
}

// ---------------- PV + head merge ----------------
__global__ __launch_bounds__(256, 2) void pv_merge(const f16* __restrict__ qkv,
                                                   const f16* __restrict__ zt,
                                                   f16* __restrict__ out2) {
  const int st = blockIdx.x;
  const int bh = blockIdx.y;
  const int b = bh >> 4, h = bh & 15;
  const f16* vg = qkv + (size_t)(b * 4096 + st * 128) * 3072 + 2048 + h * 64;

  __shared__ f16 sV[128 * 72];
  __shared__ f16 sZ[64 * 72];

  const int tid = threadIdx.x;
  const int w = tid >> 6, l = tid & 63;

#pragma unroll
  for (int p = 0; p < 4; ++p) {
    int idx = (p * 256 + tid) * 8;
    int row = idx >> 6, col = idx & 63;
    f16x8 v = *reinterpret_cast<const f16x8*>(vg + (size_t)row * 3072 + col);
    *reinterpret_cast<f16x8*>(sV + row * 72 + col) = v;
  }
#pragma unroll
  for (int p = 0; p < 2; ++p) {
    int idx = (p * 256 + tid) * 8;
    int row = idx >> 6, col = idx & 63;
    f16x8 v = *reinterpret_cast<const f16x8*>(zt + (size_t)bh * 4096 + idx);
    *reinterpret_cast<f16x8*>(sZ + row * 72 + col) = v;
  }
  __syncthreads();

  f32x4 acc[2][4] = {};
#pragma unroll
  for (int ks = 0; ks < 2; ++ks) {
    f16x8 av[2], bz[4];
#pragma unroll
    for (int m = 0; m < 2; ++m)
      av[m] = *reinterpret_cast<const f16x8*>(sV + (w * 32 + m * 16 + (l & 15)) * 72 + ks * 32 + ((l >> 4) << 3));
#pragma unroll
    for (int n = 0; n < 4; ++n)
      bz[n] = *reinterpret_cast<const f16x8*>(sZ + (n * 16 + (l & 15)) * 72 + ks * 32 + ((l >> 4) << 3));
#pragma unroll
    for (int m = 0; m < 2; ++m)
#pragma unroll
      for (int n = 0; n < 4; ++n)
        acc[m][n] = MFMA16(av[m], bz[n], acc[m][n]);
  }

#pragma unroll
  for (int m = 0; m < 2; ++m)
#pragma unroll
    for (int n = 0; n < 4; ++n)
#pragma unroll
      for (int j = 0; j < 4; ++j) {
        int s = st * 128 + w * 32 + m * 16 + ((l >> 4) << 2) + j;
        out2[(size_t)(b * 4096 + s) * 1024 + h * 64 + n * 16 + (l & 15)] = (f16)acc[m][n][j];
      }
}

// ---------------- launch ----------------
extern "C" void kernel_launch(void* const* d_in, const int* in_sizes, int n_in,
                              void* d_out, int out_size, void* d_ws, size_t ws_size,
                              hipStream_t stream) {
  const float* x  = (const float*)d_in[0];
  const float* Wq = (const float*)d_in[1];
  const float* Wk = (const float*)d_in[2];
  const float* Wv = (const float*)d_in[3];
  const float* Wo = (const float*)d_in[4];
  float* out = (float*)d_out;

  f16* xh    = (f16*)d_ws;               //  33,554,432  x (f16); dead after QKV GEMM
  f16* qkvh  = xh + 33554432;            // 100,663,296  [32768 x 3072] q|k|v
  f16* wqkvh = qkvh + 100663296;         //   3,145,728  [3072 x 1024]
  f16* woh   = wqkvh + 3145728;          //   1,048,576  [1024 x 1024]
  f16* zth   = woh + 1048576;            //     524,288  [128][64 zq][64 kd]
  f16* out2h = zth + 524288;             //  33,554,432  [32768 x 1024] merged
  f16* part  = (f16*)d_ws;               // 16.8 MB f16 partial scores — reuses dead xh

  cast_f32_to_f16<<<32768, 256, 0, stream>>>(x, xh, 33554432 / 4);
  cast_weights<<<4096, 256, 0, stream>>>(Wq, Wk, Wv, Wo, wqkvh, woh);

  // QKV projection: [32768,3072] = xh * Wqkv^T   (1536 blocks, %8==0, bx fast)
  gemm_bt_8ph<f16><<<128 * 12, 512, 0, stream>>>(xh, wqkvh, qkvh, 3072, 12);

  // scores: 16-way split K-reduction (2048 blocks), then combine + softmax
  scores_part<<<dim3(16, 128), 256, 0, stream>>>(qkvh, part);
  scores_combine<<<128, 256, 0, stream>>>(part, zth);

  pv_merge<<<dim3(32, 128), 256, 0, stream>>>(qkvh, zth, out2h);

  // output projection: d_out = out2 * Wo^T (f32 out)   (512 blocks, %8==0, bx fast)
  gemm_bt_8ph<float><<<128 * 4, 512, 0, stream>>>(out2h, woh, out, 1024, 4);
}